// Round 15
// baseline (1499.806 us; speedup 1.0000x reference)
//
#include <hip/hip_runtime.h>
#include <stdint.h>

#define NE 500000
#define NN 50000
#define ND 256
#define ED 128
#define GD 64
#define MAXDEG 64

typedef float f4v __attribute__((ext_vector_type(4)));
typedef short s8v __attribute__((ext_vector_type(8)));
typedef short s4v __attribute__((ext_vector_type(4)));

static __device__ __forceinline__ short f2bf(float f) {
  union { float f; uint32_t u; } v; v.f = f;
  uint32_t r = v.u + 0x7FFFu + ((v.u >> 16) & 1u);
  return (short)(r >> 16);
}
static __device__ __forceinline__ float bf2f(uint32_t u) {
  union { uint32_t u; float f; } v; v.u = u << 16; return v.f;
}

// ---- pack W[K][C] fp32 -> bf16 MFMA fragment order [ks][c][kh][j] ----
static __device__ __forceinline__ void pack_one(const float* __restrict__ src,
                                                short* __restrict__ dst, int C, int idx) {
  int k = idx / C, c = idx - k * C;
  int ks = k >> 5, kh = (k >> 3) & 3, j = k & 7;
  dst[(((ks * C + c) * 4 + kh) << 3) + j] = f2bf(src[idx]);
}

// =======================================================================
// Fused prep: x->bf16 cvt | pack W1..W4 | build per-dest elist.
// =======================================================================
#define J0 3200000   // cvt: NN*ND/4 threads, 4 elems each
#define J1 196608    // w1p 384x512
#define J2 65536     // w2p 512x128
#define J3 458752    // w3p 448x1024
#define J4 262144    // w4p 1024x256
#define J5 500000    // build elist
__global__ void prep_kernel(const float* __restrict__ x, short* __restrict__ xbf,
                            const float* __restrict__ W1, const float* __restrict__ W2,
                            const float* __restrict__ W3, const float* __restrict__ W4,
                            short* __restrict__ w1p, short* __restrict__ w2p,
                            short* __restrict__ w3p, short* __restrict__ w4p,
                            const int* __restrict__ ecol, unsigned int* __restrict__ cnt,
                            int* __restrict__ elist) {
  int idx = blockIdx.x * blockDim.x + threadIdx.x;
  if (idx < J0) {
    int i = idx * 4;
    const float4 v = *(const float4*)(x + i);
    s4v o; o[0] = f2bf(v.x); o[1] = f2bf(v.y); o[2] = f2bf(v.z); o[3] = f2bf(v.w);
    *(s4v*)(xbf + i) = o;
    return;
  }
  idx -= J0;
  if (idx < J1) { pack_one(W1, w1p, 512, idx); return; }
  idx -= J1;
  if (idx < J2) { pack_one(W2, w2p, 128, idx); return; }
  idx -= J2;
  if (idx < J3) { pack_one(W3, w3p, 1024, idx); return; }
  idx -= J3;
  if (idx < J4) { pack_one(W4, w4p, 256, idx); return; }
  idx -= J4;
  if (idx < J5) {
    int c = ecol[idx];
    unsigned int slot = atomicAdd(&cnt[c], 1u);
    if (slot < MAXDEG) elist[c * MAXDEG + slot] = idx;
  }
}

// ---- gather-mean: one wave per node, lane handles 2 dims ----
__global__ void agg_kernel(const unsigned short* __restrict__ ebuf,
                           const int* __restrict__ elist,
                           const unsigned int* __restrict__ cnt,
                           unsigned short* __restrict__ aggbf) {
  int tid = threadIdx.x;
  int lane = tid & 63;
  int node = blockIdx.x * 4 + (tid >> 6);
  if (node >= NN) return;
  unsigned int deg = cnt[node];
  unsigned int jend = deg < MAXDEG ? deg : MAXDEG;
  float a0 = 0.f, a1 = 0.f;
  const int* el = elist + (size_t)node * MAXDEG;
  for (unsigned int j = 0; j < jend; ++j) {
    int eid = el[j];
    uint32_t v = *(const uint32_t*)(ebuf + (size_t)eid * ED + 2 * lane);
    a0 += bf2f(v & 0xFFFFu);
    a1 += bf2f(v >> 16);
  }
  float rc = 1.0f / (deg > 0 ? (float)deg : 1.0f);
  uint32_t o = (uint32_t)(uint16_t)f2bf(a0 * rc) | ((uint32_t)(uint16_t)f2bf(a1 * rc) << 16);
  *(uint32_t*)(aggbf + (size_t)node * ED + 2 * lane) = o;
}

// =======================================================================
// Edge kernel: M=128 edges/WG, 16 waves. STAGING-FREE GEMM1: X (xbf) and
// E (ea, cvt in-loop) fragments are 16B/32B contiguous per-lane reads
// consumed exactly once -> read DIRECTLY from global (L2-hot), no LDS
// round-trip, no staging barriers. Only H1 lives in LDS, as 4 slices of
// [128][128] bf16 (32KB) double-buffered: write slice s+1 (its 8 waves)
// overlaps GEMM2 on slice s (all 16 waves). LDS = 64KB. Barriers = 5.
// Register budget: acc1 64 + acc2 16 + transients ~24, no cross-phase
// global-load holds (R9 spill lesson). Direct 8B epilogue stores (R14).
// =======================================================================
__launch_bounds__(1024, 4)
__global__ void edge_kernel(const short* __restrict__ xbf,
                            const float* __restrict__ edge_attr,
                            const short* __restrict__ w1p,
                            const float* __restrict__ b1,
                            const short* __restrict__ w2p,
                            const float* __restrict__ b2,
                            const int* __restrict__ erow,
                            unsigned short* __restrict__ ebuf) {
  __shared__ __align__(16) short hs[2][128 * 128];   // 2 x 32KB H1 slices
  const int tid = threadIdx.x;
  const int lane = tid & 63;
  const int w = tid >> 6;          // wave 0..15
  const int lh = lane >> 4;        // 0..3
  const int ll = lane & 15;        // 0..15
  const int e0 = blockIdx.x * 128;

  f4v acc1[2][8];
  #pragma unroll
  for (int n = 0; n < 2; ++n)
    #pragma unroll
    for (int m = 0; m < 8; ++m)
      acc1[n][m] = (f4v){0.f, 0.f, 0.f, 0.f};

  // ---- GEMM1 ks 0..7: X fragments straight from global (clamped tail) ----
  {
    int rid[8];
    #pragma unroll
    for (int m = 0; m < 8; ++m) {
      int e = e0 + 16 * m + ll;
      rid[m] = erow[e < NE ? e : NE - 1];
    }
    for (int ks = 0; ks < 8; ++ks) {
      s8v wf0 = *(const s8v*)(w1p + (((ks * 512 + w * 16 + ll) * 4 + lh) << 3));
      s8v wf1 = *(const s8v*)(w1p + (((ks * 512 + 256 + w * 16 + ll) * 4 + lh) << 3));
      #pragma unroll
      for (int m = 0; m < 8; ++m) {
        s8v hf = *(const s8v*)(xbf + (size_t)rid[m] * 256 + (ks * 4 + lh) * 8);
        acc1[0][m] = __builtin_amdgcn_mfma_f32_16x16x32_bf16(wf0, hf, acc1[0][m], 0, 0, 0);
        acc1[1][m] = __builtin_amdgcn_mfma_f32_16x16x32_bf16(wf1, hf, acc1[1][m], 0, 0, 0);
      }
    }
  }

  // ---- GEMM1 ks 8..11: E fragments from global fp32, cvt in-loop ----
  for (int ks = 8; ks < 12; ++ks) {
    s8v wf0 = *(const s8v*)(w1p + (((ks * 512 + w * 16 + ll) * 4 + lh) << 3));
    s8v wf1 = *(const s8v*)(w1p + (((ks * 512 + 256 + w * 16 + ll) * 4 + lh) << 3));
    #pragma unroll
    for (int m = 0; m < 8; ++m) {
      int e = e0 + 16 * m + ll;
      const float* pe = edge_attr + (size_t)(e < NE ? e : NE - 1) * ED + ((ks - 8) * 4 + lh) * 8;
      const float4 v0 = *(const float4*)(pe);
      const float4 v1 = *(const float4*)(pe + 4);
      s8v hf;
      hf[0] = f2bf(v0.x); hf[1] = f2bf(v0.y); hf[2] = f2bf(v0.z); hf[3] = f2bf(v0.w);
      hf[4] = f2bf(v1.x); hf[5] = f2bf(v1.y); hf[6] = f2bf(v1.z); hf[7] = f2bf(v1.w);
      acc1[0][m] = __builtin_amdgcn_mfma_f32_16x16x32_bf16(wf0, hf, acc1[0][m], 0, 0, 0);
      acc1[1][m] = __builtin_amdgcn_mfma_f32_16x16x32_bf16(wf1, hf, acc1[1][m], 0, 0, 0);
    }
  }

  // ---- H1 slice pipeline. Slice s (cols [128s,128s+128)) is written by
  //      waves with (w>>3)==(s&1) from acc1[s>>1]; local col 16*(w&7). ----
  auto write_slice = [&](int s) {
    if ((w >> 3) == (s & 1)) {
      const int n = s >> 1;
      const int lcb = (w & 7) * 16 + 4 * lh;          // local col 0..127
      const float4 bv = *(const float4*)(b1 + s * 128 + lcb);
      #pragma unroll
      for (int m = 0; m < 8; ++m) {
        int row = 16 * m + ll;
        s4v o;
        float v0 = acc1[n][m][0] + bv.x; o[0] = f2bf(v0 > 0.f ? v0 : 0.f);
        float v1 = acc1[n][m][1] + bv.y; o[1] = f2bf(v1 > 0.f ? v1 : 0.f);
        float v2 = acc1[n][m][2] + bv.z; o[2] = f2bf(v2 > 0.f ? v2 : 0.f);
        float v3 = acc1[n][m][3] + bv.w; o[3] = f2bf(v3 > 0.f ? v3 : 0.f);
        int byte = (row * 256 + lcb * 2) ^ ((row & 7) << 4);
        *(s4v*)((char*)hs[s & 1] + byte) = o;
      }
    }
  };

  write_slice(0);
  __syncthreads();

  f4v acc2[4];
  #pragma unroll
  for (int m = 0; m < 4; ++m)
    acc2[m] = (f4v){0.f, 0.f, 0.f, 0.f};

  for (int s = 0; s < 4; ++s) {
    if (s < 3) write_slice(s + 1);       // fills the other buffer
    // GEMM2 on slice s: K = [128s, 128s+128), 4 ksl
    for (int ksl = 0; ksl < 4; ++ksl) {
      int ksg = s * 4 + ksl;
      s8v wf = *(const s8v*)(w2p + (((ksg * 128 + (w & 7) * 16 + ll) * 4 + lh) << 3));
      #pragma unroll
      for (int m = 0; m < 4; ++m) {
        int row = 64 * (w >> 3) + 16 * m + ll;
        int byte = (row * 256 + ksl * 64 + lh * 16) ^ ((row & 7) << 4);
        s8v hf = *(const s8v*)((char*)hs[s & 1] + byte);
        acc2[m] = __builtin_amdgcn_mfma_f32_16x16x32_bf16(wf, hf, acc2[m], 0, 0, 0);
      }
    }
    __syncthreads();   // slice s reads done; slice s+1 writes visible
  }

  // ---- epilogue: direct 8B stores ----
  {
    int cb = (w & 7) * 16 + 4 * lh;
    const float4 bv = *(const float4*)(b2 + cb);
    #pragma unroll
    for (int m = 0; m < 4; ++m) {
      int row = 64 * (w >> 3) + 16 * m + ll;
      int e = e0 + row;
      if (e < NE) {
        s4v o;
        o[0] = f2bf(acc2[m][0] + bv.x);
        o[1] = f2bf(acc2[m][1] + bv.y);
        o[2] = f2bf(acc2[m][2] + bv.z);
        o[3] = f2bf(acc2[m][3] + bv.w);
        *(s4v*)(ebuf + (size_t)e * ED + cb) = o;
      }
    }
  }
}

// =======================================================================
// Node kernel: unchanged (R10/R14-benched, 16 waves).
// =======================================================================
__launch_bounds__(1024, 4)
__global__ void node_kernel(const float* __restrict__ x,
                            const short* __restrict__ xbf,
                            const float* __restrict__ u,
                            const short* __restrict__ w3p,
                            const float* __restrict__ b3,
                            const short* __restrict__ w4p,
                            const float* __restrict__ b4,
                            const float* __restrict__ gamma,
                            const float* __restrict__ beta,
                            const int* __restrict__ batch,
                            const unsigned short* __restrict__ aggbf,
                            float* __restrict__ out) {
  __shared__ __align__(16) short smem[64 * 1024];
  const int tid = threadIdx.x;
  const int lane = tid & 63;
  const int w = tid >> 6;
  const int lh = lane >> 4;
  const int ll = lane & 15;
  const int n0 = blockIdx.x * 64;

  #pragma unroll
  for (int it = 0; it < 4; ++it) {
    int ch = tid + it * 1024;
    if (ch < 3584) {
      int rr = ch / 56;
      int cc = (ch - rr * 56) * 8;
      s8v vals = {0, 0, 0, 0, 0, 0, 0, 0};
      int node = n0 + rr;
      if (node < NN) {
        if (cc < 256) {
          vals = *(const s8v*)(xbf + (size_t)node * ND + cc);
        } else if (cc < 384) {
          vals = *(const s8v*)(aggbf + (size_t)node * ED + (cc - 256));
        } else {
          const float* up = u + (size_t)batch[node] * GD + (cc - 384);
          const float4 v0 = *(const float4*)(up);
          const float4 v1 = *(const float4*)(up + 4);
          vals[0] = f2bf(v0.x); vals[1] = f2bf(v0.y); vals[2] = f2bf(v0.z); vals[3] = f2bf(v0.w);
          vals[4] = f2bf(v1.x); vals[5] = f2bf(v1.y); vals[6] = f2bf(v1.z); vals[7] = f2bf(v1.w);
        }
      }
      int byte = (rr * 896 + cc * 2) ^ ((rr & 7) << 4);
      *(s8v*)((char*)smem + byte) = vals;
    }
  }
  __syncthreads();

  f4v acc3[4][4];
  #pragma unroll
  for (int n = 0; n < 4; ++n)
    #pragma unroll
    for (int m = 0; m < 4; ++m)
      acc3[n][m] = (f4v){0.f, 0.f, 0.f, 0.f};

  for (int ks = 0; ks < 14; ++ks) {
    s8v af[4];
    #pragma unroll
    for (int m = 0; m < 4; ++m) {
      int row = 16 * m + ll;
      int byte = (row * 896 + ks * 64 + lh * 16) ^ ((row & 7) << 4);
      af[m] = *(const s8v*)((const char*)smem + byte);
    }
    #pragma unroll
    for (int n = 0; n < 4; ++n) {
      s8v wf = *(const s8v*)(w3p + (((ks * 1024 + w * 64 + 16 * n + ll) * 4 + lh) << 3));
      #pragma unroll
      for (int m = 0; m < 4; ++m)
        acc3[n][m] = __builtin_amdgcn_mfma_f32_16x16x32_bf16(wf, af[m], acc3[n][m], 0, 0, 0);
    }
  }
  __syncthreads();

  #pragma unroll
  for (int n = 0; n < 4; ++n) {
    int cb = w * 64 + 16 * n + 4 * lh;
    const float4 bv = *(const float4*)(b3 + cb);
    #pragma unroll
    for (int m = 0; m < 4; ++m) {
      int row = 16 * m + ll;
      s4v o;
      float v0 = acc3[n][m][0] + bv.x; o[0] = f2bf(v0 > 0.f ? v0 : 0.f);
      float v1 = acc3[n][m][1] + bv.y; o[1] = f2bf(v1 > 0.f ? v1 : 0.f);
      float v2 = acc3[n][m][2] + bv.z; o[2] = f2bf(v2 > 0.f ? v2 : 0.f);
      float v3 = acc3[n][m][3] + bv.w; o[3] = f2bf(v3 > 0.f ? v3 : 0.f);
      int byte = (row * 2048 + cb * 2) ^ ((row & 7) << 4);
      *(s4v*)((char*)smem + byte) = o;
    }
  }
  __syncthreads();

  f4v acc4[4];
  #pragma unroll
  for (int m = 0; m < 4; ++m)
    acc4[m] = (f4v){0.f, 0.f, 0.f, 0.f};

  for (int ks = 0; ks < 32; ++ks) {
    s8v wf = *(const s8v*)(w4p + (((ks * 256 + w * 16 + ll) * 4 + lh) << 3));
    #pragma unroll
    for (int m = 0; m < 4; ++m) {
      int row = 16 * m + ll;
      int byte = (row * 2048 + ks * 64 + lh * 16) ^ ((row & 7) << 4);
      s8v hf = *(const s8v*)((const char*)smem + byte);
      acc4[m] = __builtin_amdgcn_mfma_f32_16x16x32_bf16(wf, hf, acc4[m], 0, 0, 0);
    }
  }
  __syncthreads();

  float* yb = (float*)smem;
  {
    int cb = w * 16 + 4 * lh;
    const float4 bv = *(const float4*)(b4 + cb);
    #pragma unroll
    for (int m = 0; m < 4; ++m) {
      int row = 16 * m + ll;
      int node = n0 + row;
      float4 xv = {0.f, 0.f, 0.f, 0.f};
      if (node < NN) xv = *(const float4*)(x + (size_t)node * ND + cb);
      f4v o;
      o[0] = acc4[m][0] + bv.x + xv.x;
      o[1] = acc4[m][1] + bv.y + xv.y;
      o[2] = acc4[m][2] + bv.z + xv.z;
      o[3] = acc4[m][3] + bv.w + xv.w;
      *(f4v*)(yb + row * 260 + cb) = o;
    }
  }
  __syncthreads();

  {
    int row = tid >> 4, sub = tid & 15;
    int node = n0 + row;
    float v[16];
    float sum = 0.f, ssq = 0.f;
    #pragma unroll
    for (int i = 0; i < 4; ++i) {
      const float4 t = *(const float4*)(yb + row * 260 + (i * 16 + sub) * 4);
      v[i * 4 + 0] = t.x; v[i * 4 + 1] = t.y; v[i * 4 + 2] = t.z; v[i * 4 + 3] = t.w;
      sum += t.x + t.y + t.z + t.w;
      ssq += t.x * t.x + t.y * t.y + t.z * t.z + t.w * t.w;
    }
    #pragma unroll
    for (int d = 1; d < 16; d <<= 1) {
      sum += __shfl_xor(sum, d);
      ssq += __shfl_xor(ssq, d);
    }
    float mu = sum * (1.f / 256.f);
    float var = ssq * (1.f / 256.f) - mu * mu;
    float rstd = rsqrtf(var + 1e-5f);
    if (node < NN) {
      #pragma unroll
      for (int i = 0; i < 4; ++i) {
        int c = (i * 16 + sub) * 4;
        const float4 g = *(const float4*)(gamma + c);
        const float4 be = *(const float4*)(beta + c);
        float4 o;
        o.x = (v[i * 4 + 0] - mu) * rstd * g.x + be.x;
        o.y = (v[i * 4 + 1] - mu) * rstd * g.y + be.y;
        o.z = (v[i * 4 + 2] - mu) * rstd * g.z + be.z;
        o.w = (v[i * 4 + 3] - mu) * rstd * g.w + be.w;
        *(float4*)(out + (size_t)node * ND + c) = o;
      }
    }
  }
}

extern "C" void kernel_launch(void* const* d_in, const int* in_sizes, int n_in,
                              void* d_out, int out_size, void* d_ws, size_t ws_size,
                              hipStream_t stream) {
  const float* x    = (const float*)d_in[0];
  const float* ea   = (const float*)d_in[1];
  const float* u    = (const float*)d_in[2];
  const float* W1   = (const float*)d_in[3];
  const float* b1   = (const float*)d_in[4];
  const float* W2   = (const float*)d_in[5];
  const float* b2   = (const float*)d_in[6];
  const float* W3   = (const float*)d_in[7];
  const float* b3   = (const float*)d_in[8];
  const float* W4   = (const float*)d_in[9];
  const float* b4   = (const float*)d_in[10];
  const float* gamma = (const float*)d_in[11];
  const float* beta  = (const float*)d_in[12];
  const int* eidx   = (const int*)d_in[13];
  const int* batch  = (const int*)d_in[14];
  float* out = (float*)d_out;

  char* p = (char*)d_ws;
  size_t off = 0;
  auto take = [&](size_t n) { char* r = p + off; off = (off + n + 255) & ~(size_t)255; return r; };
  short* xbf = (short*)take((size_t)NN * ND * 2);
  short* w1p = (short*)take((size_t)384 * 512 * 2);
  short* w2p = (short*)take((size_t)512 * 128 * 2);
  short* w3p = (short*)take((size_t)448 * 1024 * 2);
  short* w4p = (short*)take((size_t)1024 * 256 * 2);
  unsigned int* cnt = (unsigned int*)take((size_t)NN * 4);
  int* elist = (int*)take((size_t)NN * MAXDEG * 4);
  unsigned short* aggbf = (unsigned short*)take((size_t)NN * ED * 2);
  unsigned short* ebuf = (unsigned short*)take((size_t)NE * ED * 2);

  const int* erow = eidx;
  const int* ecol = eidx + NE;

  hipMemsetAsync(cnt, 0, (size_t)NN * 4, stream);
  {
    const int total = J0 + J1 + J2 + J3 + J4 + J5;
    prep_kernel<<<(total + 255) / 256, 256, 0, stream>>>(x, xbf, W1, W2, W3, W4,
                                                         w1p, w2p, w3p, w4p,
                                                         ecol, cnt, elist);
  }
  edge_kernel<<<(NE + 127) / 128, 1024, 0, stream>>>(xbf, ea, w1p, b1, w2p, b2, erow, ebuf);
  agg_kernel<<<(NN + 3) / 4, 256, 0, stream>>>(ebuf, elist, cnt, aggbf);
  node_kernel<<<(NN + 63) / 64, 1024, 0, stream>>>(x, xbf, u, w3p, b3, w4p, b4,
                                                   gamma, beta, batch, aggbf, out);
}

// Round 16
// 658.242 us; speedup vs baseline: 2.2785x; 2.2785x over previous
//
#include <hip/hip_runtime.h>
#include <stdint.h>

#define NE 500000
#define NN 50000
#define ND 256
#define ED 128
#define GD 64
#define MAXDEG 64

typedef float f4v __attribute__((ext_vector_type(4)));
typedef short s8v __attribute__((ext_vector_type(8)));
typedef short s4v __attribute__((ext_vector_type(4)));

static __device__ __forceinline__ short f2bf(float f) {
  union { float f; uint32_t u; } v; v.f = f;
  uint32_t r = v.u + 0x7FFFu + ((v.u >> 16) & 1u);
  return (short)(r >> 16);
}
static __device__ __forceinline__ float bf2f(uint32_t u) {
  union { uint32_t u; float f; } v; v.u = u << 16; return v.f;
}

// ---- async global->LDS DMA, 16B per lane ----
static __device__ __forceinline__ void gload_lds16(const void* g, void* l) {
  __builtin_amdgcn_global_load_lds(
      (const __attribute__((address_space(1))) unsigned int*)g,
      (__attribute__((address_space(3))) unsigned int*)l,
      16, 0, 0);
}

// ---- pack W[K][C] fp32 -> bf16 MFMA fragment order [ks][c][kh][j] ----
static __device__ __forceinline__ void pack_one(const float* __restrict__ src,
                                                short* __restrict__ dst, int C, int idx) {
  int k = idx / C, c = idx - k * C;
  int ks = k >> 5, kh = (k >> 3) & 3, j = k & 7;
  dst[(((ks * C + c) * 4 + kh) << 3) + j] = f2bf(src[idx]);
}

// =======================================================================
// Fused prep: x->bf16 cvt | pack W1..W4 | build per-dest elist.
// =======================================================================
#define J0 3200000   // cvt: NN*ND/4 threads, 4 elems each
#define J1 196608    // w1p 384x512
#define J2 65536     // w2p 512x128
#define J3 458752    // w3p 448x1024
#define J4 262144    // w4p 1024x256
#define J5 500000    // build elist
__global__ void prep_kernel(const float* __restrict__ x, short* __restrict__ xbf,
                            const float* __restrict__ W1, const float* __restrict__ W2,
                            const float* __restrict__ W3, const float* __restrict__ W4,
                            short* __restrict__ w1p, short* __restrict__ w2p,
                            short* __restrict__ w3p, short* __restrict__ w4p,
                            const int* __restrict__ ecol, unsigned int* __restrict__ cnt,
                            int* __restrict__ elist) {
  int idx = blockIdx.x * blockDim.x + threadIdx.x;
  if (idx < J0) {
    int i = idx * 4;
    const float4 v = *(const float4*)(x + i);
    s4v o; o[0] = f2bf(v.x); o[1] = f2bf(v.y); o[2] = f2bf(v.z); o[3] = f2bf(v.w);
    *(s4v*)(xbf + i) = o;
    return;
  }
  idx -= J0;
  if (idx < J1) { pack_one(W1, w1p, 512, idx); return; }
  idx -= J1;
  if (idx < J2) { pack_one(W2, w2p, 128, idx); return; }
  idx -= J2;
  if (idx < J3) { pack_one(W3, w3p, 1024, idx); return; }
  idx -= J3;
  if (idx < J4) { pack_one(W4, w4p, 256, idx); return; }
  idx -= J4;
  if (idx < J5) {
    int c = ecol[idx];
    unsigned int slot = atomicAdd(&cnt[c], 1u);
    if (slot < MAXDEG) elist[c * MAXDEG + slot] = idx;
  }
}

// =======================================================================
// gather-mean: one wave per node, 4 edges per iteration.
// Lane l: j-group (l>>4), 16B dim-chunk (l&15). Each edge row (256B) is
// read as 16 coalesced 16B loads; cross-group sum via shfl_xor(16,32).
// =======================================================================
__global__ void agg_kernel(const unsigned short* __restrict__ ebuf,
                           const int* __restrict__ elist,
                           const unsigned int* __restrict__ cnt,
                           unsigned short* __restrict__ aggbf) {
  int tid = threadIdx.x;
  int lane = tid & 63;
  int node = blockIdx.x * 4 + (tid >> 6);
  if (node >= NN) return;
  unsigned int deg = cnt[node];
  unsigned int jend = deg < MAXDEG ? deg : MAXDEG;
  const int jg = lane >> 4;        // 0..3
  const int ch = lane & 15;        // 16B chunk within row
  float a[8] = {0.f, 0.f, 0.f, 0.f, 0.f, 0.f, 0.f, 0.f};
  const int* el = elist + (size_t)node * MAXDEG;
  for (unsigned int j = jg; j < jend; j += 4) {
    int eid = el[j];
    s8v v = *(const s8v*)(ebuf + (size_t)eid * ED + ch * 8);
    #pragma unroll
    for (int i = 0; i < 8; ++i) a[i] += bf2f((uint32_t)(uint16_t)v[i]);
  }
  #pragma unroll
  for (int d = 16; d < 64; d <<= 1) {
    #pragma unroll
    for (int i = 0; i < 8; ++i) a[i] += __shfl_xor(a[i], d);
  }
  if (jg == 0) {
    float rc = 1.0f / (deg > 0 ? (float)deg : 1.0f);
    s8v o;
    #pragma unroll
    for (int i = 0; i < 8; ++i) o[i] = f2bf(a[i] * rc);
    *(s8v*)(aggbf + (size_t)node * ED + ch * 8) = o;
  }
}

// =======================================================================
// Edge kernel: EXACT R14-benched version (399us, MfmaUtil 28.7, clean).
//  - X [128][256]bf16 (64KB) staged by global_load_lds, SOURCE-swizzled
//    octet (c ^ (row&7)); E [128][128]bf16 (32KB) staged fp32->bf16 by
//    VALU concurrently with the X DMA.
//  - H1 in two [128][256] half passes (64KB region).
//  - direct 8B epilogue stores.  Barriers = 4.
// LESSONS FROZEN IN: (R9) no global loads held in registers across MFMA
// phases -> spill; (R15) no per-lane multi-row fragment reads from global
// feeding MFMA directly -> uncoalesced latency disaster. LDS staging of
// the A-operand is for TRANSACTION SHAPING, not just reuse.
// =======================================================================
__launch_bounds__(1024, 4)
__global__ void edge_kernel(const short* __restrict__ xbf,
                            const float* __restrict__ edge_attr,
                            const short* __restrict__ w1p,
                            const float* __restrict__ b1,
                            const short* __restrict__ w2p,
                            const float* __restrict__ b2,
                            const int* __restrict__ erow,
                            unsigned short* __restrict__ ebuf) {
  __shared__ __align__(16) short smem[81920];       // 160KB
  char* const Xb = (char*)smem;                     // [128][256] bf16, 512B rows
  char* const Eb = (char*)smem + 65536;             // [128][128] bf16, 256B rows
  char* const Hb = (char*)smem + 98304;             // H1 half [128][256], XOR swz
  const int tid = threadIdx.x;
  const int lane = tid & 63;
  const int w = tid >> 6;          // wave 0..15
  const int lh = lane >> 4;        // 0..3
  const int ll = lane & 15;        // 0..15
  const int e0 = blockIdx.x * 128;

  // ---- X: DMA xbf rows (1KB = 2 rows per inst, 4 insts per wave) ----
  {
    #pragma unroll
    for (int i = 0; i < 4; ++i) {
      int p = w * 4 + i;                     // row pair 0..63
      int row = 2 * p + (lane >> 5);
      int rid = erow[e0 + row];              // tail reads stay in eidx buffer
      int cg = (lane & 31) ^ (row & 7);      // source-swizzled octet
      gload_lds16(xbf + (size_t)rid * 256 + cg * 8, Xb + p * 1024);
    }
  }

  // ---- E: stage ea fp32 -> bf16, octet-swizzled (concurrent with DMA) ----
  #pragma unroll
  for (int it = 0; it < 2; ++it) {
    int id = tid + it * 1024;                // 2048 octets
    int row = id >> 4, oct = id & 15;
    s8v vals = {0, 0, 0, 0, 0, 0, 0, 0};
    if (e0 + row < NE) {
      const float* p = edge_attr + (size_t)(e0 + row) * ED + oct * 8;
      const float4 v0 = *(const float4*)(p);
      const float4 v1 = *(const float4*)(p + 4);
      vals[0] = f2bf(v0.x); vals[1] = f2bf(v0.y); vals[2] = f2bf(v0.z); vals[3] = f2bf(v0.w);
      vals[4] = f2bf(v1.x); vals[5] = f2bf(v1.y); vals[6] = f2bf(v1.z); vals[7] = f2bf(v1.w);
    }
    *(s8v*)(Eb + row * 256 + ((oct ^ (row & 7)) << 4)) = vals;
  }
  __syncthreads();   // drains vmcnt (DMA complete) + E writes visible

  // ---- GEMM1 (swapped): acc1[n][mt]; n=0 -> cols 16w, n=1 -> 256+16w ----
  f4v acc1[2][8];
  #pragma unroll
  for (int n = 0; n < 2; ++n)
    #pragma unroll
    for (int m = 0; m < 8; ++m)
      acc1[n][m] = (f4v){0.f, 0.f, 0.f, 0.f};

  // ks 0..7: k<256 from X
  for (int ks = 0; ks < 8; ++ks) {
    s8v wf0 = *(const s8v*)(w1p + (((ks * 512 + w * 16 + ll) * 4 + lh) << 3));
    s8v wf1 = *(const s8v*)(w1p + (((ks * 512 + 256 + w * 16 + ll) * 4 + lh) << 3));
    #pragma unroll
    for (int mh = 0; mh < 2; ++mh) {
      s8v hf[4];
      #pragma unroll
      for (int m = 0; m < 4; ++m) {
        int row = 64 * mh + 16 * m + ll;
        int byte = row * 512 + (((ks * 4 + lh) ^ (row & 7)) << 4);
        hf[m] = *(const s8v*)(Xb + byte);
      }
      #pragma unroll
      for (int m = 0; m < 4; ++m) {
        acc1[0][4 * mh + m] = __builtin_amdgcn_mfma_f32_16x16x32_bf16(wf0, hf[m], acc1[0][4 * mh + m], 0, 0, 0);
        acc1[1][4 * mh + m] = __builtin_amdgcn_mfma_f32_16x16x32_bf16(wf1, hf[m], acc1[1][4 * mh + m], 0, 0, 0);
      }
    }
  }
  // ks 8..11: k>=256 from E
  for (int ks = 8; ks < 12; ++ks) {
    s8v wf0 = *(const s8v*)(w1p + (((ks * 512 + w * 16 + ll) * 4 + lh) << 3));
    s8v wf1 = *(const s8v*)(w1p + (((ks * 512 + 256 + w * 16 + ll) * 4 + lh) << 3));
    #pragma unroll
    for (int mh = 0; mh < 2; ++mh) {
      s8v hf[4];
      #pragma unroll
      for (int m = 0; m < 4; ++m) {
        int row = 64 * mh + 16 * m + ll;
        int byte = row * 256 + ((((ks - 8) * 4 + lh) ^ (row & 7)) << 4);
        hf[m] = *(const s8v*)(Eb + byte);
      }
      #pragma unroll
      for (int m = 0; m < 4; ++m) {
        acc1[0][4 * mh + m] = __builtin_amdgcn_mfma_f32_16x16x32_bf16(wf0, hf[m], acc1[0][4 * mh + m], 0, 0, 0);
        acc1[1][4 * mh + m] = __builtin_amdgcn_mfma_f32_16x16x32_bf16(wf1, hf[m], acc1[1][4 * mh + m], 0, 0, 0);
      }
    }
  }

  // ---- GEMM2 accumulators: c2-tile (w&7), edge-quarter (w>>3) ----
  f4v acc2[4];
  #pragma unroll
  for (int m = 0; m < 4; ++m)
    acc2[m] = (f4v){0.f, 0.f, 0.f, 0.f};

  // ---- half 0: write H1 -> barrier -> GEMM2 K=256 ----
  {
    int lcb = w * 16 + 4 * lh;
    const float4 bv = *(const float4*)(b1 + lcb);
    #pragma unroll
    for (int m = 0; m < 8; ++m) {
      int row = 16 * m + ll;
      s4v o;
      float v0 = acc1[0][m][0] + bv.x; o[0] = f2bf(v0 > 0.f ? v0 : 0.f);
      float v1 = acc1[0][m][1] + bv.y; o[1] = f2bf(v1 > 0.f ? v1 : 0.f);
      float v2 = acc1[0][m][2] + bv.z; o[2] = f2bf(v2 > 0.f ? v2 : 0.f);
      float v3 = acc1[0][m][3] + bv.w; o[3] = f2bf(v3 > 0.f ? v3 : 0.f);
      int byte = (row * 512 + lcb * 2) ^ ((row & 7) << 4);
      *(s4v*)(Hb + byte) = o;
    }
  }
  __syncthreads();

  for (int ksl = 0; ksl < 8; ++ksl) {
    s8v wf = *(const s8v*)(w2p + (((ksl * 128 + (w & 7) * 16 + ll) * 4 + lh) << 3));
    #pragma unroll
    for (int m = 0; m < 4; ++m) {
      int row = 64 * (w >> 3) + 16 * m + ll;
      int byte = (row * 512 + ksl * 64 + lh * 16) ^ ((row & 7) << 4);
      s8v hf = *(const s8v*)(Hb + byte);
      acc2[m] = __builtin_amdgcn_mfma_f32_16x16x32_bf16(wf, hf, acc2[m], 0, 0, 0);
    }
  }
  __syncthreads();   // half-0 reads done before overwrite

  // ---- half 1 ----
  {
    int lcb = w * 16 + 4 * lh;
    const float4 bv = *(const float4*)(b1 + 256 + lcb);
    #pragma unroll
    for (int m = 0; m < 8; ++m) {
      int row = 16 * m + ll;
      s4v o;
      float v0 = acc1[1][m][0] + bv.x; o[0] = f2bf(v0 > 0.f ? v0 : 0.f);
      float v1 = acc1[1][m][1] + bv.y; o[1] = f2bf(v1 > 0.f ? v1 : 0.f);
      float v2 = acc1[1][m][2] + bv.z; o[2] = f2bf(v2 > 0.f ? v2 : 0.f);
      float v3 = acc1[1][m][3] + bv.w; o[3] = f2bf(v3 > 0.f ? v3 : 0.f);
      int byte = (row * 512 + lcb * 2) ^ ((row & 7) << 4);
      *(s4v*)(Hb + byte) = o;
    }
  }
  __syncthreads();

  for (int ksl = 0; ksl < 8; ++ksl) {
    int ksg = 8 + ksl;
    s8v wf = *(const s8v*)(w2p + (((ksg * 128 + (w & 7) * 16 + ll) * 4 + lh) << 3));
    #pragma unroll
    for (int m = 0; m < 4; ++m) {
      int row = 64 * (w >> 3) + 16 * m + ll;
      int byte = (row * 512 + ksl * 64 + lh * 16) ^ ((row & 7) << 4);
      s8v hf = *(const s8v*)(Hb + byte);
      acc2[m] = __builtin_amdgcn_mfma_f32_16x16x32_bf16(wf, hf, acc2[m], 0, 0, 0);
    }
  }

  // ---- epilogue: direct 8B stores ----
  {
    int cb = (w & 7) * 16 + 4 * lh;
    const float4 bv = *(const float4*)(b2 + cb);
    #pragma unroll
    for (int m = 0; m < 4; ++m) {
      int row = 64 * (w >> 3) + 16 * m + ll;
      int e = e0 + row;
      if (e < NE) {
        s4v o;
        o[0] = f2bf(acc2[m][0] + bv.x);
        o[1] = f2bf(acc2[m][1] + bv.y);
        o[2] = f2bf(acc2[m][2] + bv.z);
        o[3] = f2bf(acc2[m][3] + bv.w);
        *(s4v*)(ebuf + (size_t)e * ED + cb) = o;
      }
    }
  }
}

// =======================================================================
// Node kernel: unchanged (R10/R14-benched, 16 waves).
// =======================================================================
__launch_bounds__(1024, 4)
__global__ void node_kernel(const float* __restrict__ x,
                            const short* __restrict__ xbf,
                            const float* __restrict__ u,
                            const short* __restrict__ w3p,
                            const float* __restrict__ b3,
                            const short* __restrict__ w4p,
                            const float* __restrict__ b4,
                            const float* __restrict__ gamma,
                            const float* __restrict__ beta,
                            const int* __restrict__ batch,
                            const unsigned short* __restrict__ aggbf,
                            float* __restrict__ out) {
  __shared__ __align__(16) short smem[64 * 1024];
  const int tid = threadIdx.x;
  const int lane = tid & 63;
  const int w = tid >> 6;
  const int lh = lane >> 4;
  const int ll = lane & 15;
  const int n0 = blockIdx.x * 64;

  #pragma unroll
  for (int it = 0; it < 4; ++it) {
    int ch = tid + it * 1024;
    if (ch < 3584) {
      int rr = ch / 56;
      int cc = (ch - rr * 56) * 8;
      s8v vals = {0, 0, 0, 0, 0, 0, 0, 0};
      int node = n0 + rr;
      if (node < NN) {
        if (cc < 256) {
          vals = *(const s8v*)(xbf + (size_t)node * ND + cc);
        } else if (cc < 384) {
          vals = *(const s8v*)(aggbf + (size_t)node * ED + (cc - 256));
        } else {
          const float* up = u + (size_t)batch[node] * GD + (cc - 384);
          const float4 v0 = *(const float4*)(up);
          const float4 v1 = *(const float4*)(up + 4);
          vals[0] = f2bf(v0.x); vals[1] = f2bf(v0.y); vals[2] = f2bf(v0.z); vals[3] = f2bf(v0.w);
          vals[4] = f2bf(v1.x); vals[5] = f2bf(v1.y); vals[6] = f2bf(v1.z); vals[7] = f2bf(v1.w);
        }
      }
      int byte = (rr * 896 + cc * 2) ^ ((rr & 7) << 4);
      *(s8v*)((char*)smem + byte) = vals;
    }
  }
  __syncthreads();

  f4v acc3[4][4];
  #pragma unroll
  for (int n = 0; n < 4; ++n)
    #pragma unroll
    for (int m = 0; m < 4; ++m)
      acc3[n][m] = (f4v){0.f, 0.f, 0.f, 0.f};

  for (int ks = 0; ks < 14; ++ks) {
    s8v af[4];
    #pragma unroll
    for (int m = 0; m < 4; ++m) {
      int row = 16 * m + ll;
      int byte = (row * 896 + ks * 64 + lh * 16) ^ ((row & 7) << 4);
      af[m] = *(const s8v*)((const char*)smem + byte);
    }
    #pragma unroll
    for (int n = 0; n < 4; ++n) {
      s8v wf = *(const s8v*)(w3p + (((ks * 1024 + w * 64 + 16 * n + ll) * 4 + lh) << 3));
      #pragma unroll
      for (int m = 0; m < 4; ++m)
        acc3[n][m] = __builtin_amdgcn_mfma_f32_16x16x32_bf16(wf, af[m], acc3[n][m], 0, 0, 0);
    }
  }
  __syncthreads();

  #pragma unroll
  for (int n = 0; n < 4; ++n) {
    int cb = w * 64 + 16 * n + 4 * lh;
    const float4 bv = *(const float4*)(b3 + cb);
    #pragma unroll
    for (int m = 0; m < 4; ++m) {
      int row = 16 * m + ll;
      s4v o;
      float v0 = acc3[n][m][0] + bv.x; o[0] = f2bf(v0 > 0.f ? v0 : 0.f);
      float v1 = acc3[n][m][1] + bv.y; o[1] = f2bf(v1 > 0.f ? v1 : 0.f);
      float v2 = acc3[n][m][2] + bv.z; o[2] = f2bf(v2 > 0.f ? v2 : 0.f);
      float v3 = acc3[n][m][3] + bv.w; o[3] = f2bf(v3 > 0.f ? v3 : 0.f);
      int byte = (row * 2048 + cb * 2) ^ ((row & 7) << 4);
      *(s4v*)((char*)smem + byte) = o;
    }
  }
  __syncthreads();

  f4v acc4[4];
  #pragma unroll
  for (int m = 0; m < 4; ++m)
    acc4[m] = (f4v){0.f, 0.f, 0.f, 0.f};

  for (int ks = 0; ks < 32; ++ks) {
    s8v wf = *(const s8v*)(w4p + (((ks * 256 + w * 16 + ll) * 4 + lh) << 3));
    #pragma unroll
    for (int m = 0; m < 4; ++m) {
      int row = 16 * m + ll;
      int byte = (row * 2048 + ks * 64 + lh * 16) ^ ((row & 7) << 4);
      s8v hf = *(const s8v*)((const char*)smem + byte);
      acc4[m] = __builtin_amdgcn_mfma_f32_16x16x32_bf16(wf, hf, acc4[m], 0, 0, 0);
    }
  }
  __syncthreads();

  float* yb = (float*)smem;
  {
    int cb = w * 16 + 4 * lh;
    const float4 bv = *(const float4*)(b4 + cb);
    #pragma unroll
    for (int m = 0; m < 4; ++m) {
      int row = 16 * m + ll;
      int node = n0 + row;
      float4 xv = {0.f, 0.f, 0.f, 0.f};
      if (node < NN) xv = *(const float4*)(x + (size_t)node * ND + cb);
      f4v o;
      o[0] = acc4[m][0] + bv.x + xv.x;
      o[1] = acc4[m][1] + bv.y + xv.y;
      o[2] = acc4[m][2] + bv.z + xv.z;
      o[3] = acc4[m][3] + bv.w + xv.w;
      *(f4v*)(yb + row * 260 + cb) = o;
    }
  }
  __syncthreads();

  {
    int row = tid >> 4, sub = tid & 15;
    int node = n0 + row;
    float v[16];
    float sum = 0.f, ssq = 0.f;
    #pragma unroll
    for (int i = 0; i < 4; ++i) {
      const float4 t = *(const float4*)(yb + row * 260 + (i * 16 + sub) * 4);
      v[i * 4 + 0] = t.x; v[i * 4 + 1] = t.y; v[i * 4 + 2] = t.z; v[i * 4 + 3] = t.w;
      sum += t.x + t.y + t.z + t.w;
      ssq += t.x * t.x + t.y * t.y + t.z * t.z + t.w * t.w;
    }
    #pragma unroll
    for (int d = 1; d < 16; d <<= 1) {
      sum += __shfl_xor(sum, d);
      ssq += __shfl_xor(ssq, d);
    }
    float mu = sum * (1.f / 256.f);
    float var = ssq * (1.f / 256.f) - mu * mu;
    float rstd = rsqrtf(var + 1e-5f);
    if (node < NN) {
      #pragma unroll
      for (int i = 0; i < 4; ++i) {
        int c = (i * 16 + sub) * 4;
        const float4 g = *(const float4*)(gamma + c);
        const float4 be = *(const float4*)(beta + c);
        float4 o;
        o.x = (v[i * 4 + 0] - mu) * rstd * g.x + be.x;
        o.y = (v[i * 4 + 1] - mu) * rstd * g.y + be.y;
        o.z = (v[i * 4 + 2] - mu) * rstd * g.z + be.z;
        o.w = (v[i * 4 + 3] - mu) * rstd * g.w + be.w;
        *(float4*)(out + (size_t)node * ND + c) = o;
      }
    }
  }
}

extern "C" void kernel_launch(void* const* d_in, const int* in_sizes, int n_in,
                              void* d_out, int out_size, void* d_ws, size_t ws_size,
                              hipStream_t stream) {
  const float* x    = (const float*)d_in[0];
  const float* ea   = (const float*)d_in[1];
  const float* u    = (const float*)d_in[2];
  const float* W1   = (const float*)d_in[3];
  const float* b1   = (const float*)d_in[4];
  const float* W2   = (const float*)d_in[5];
  const float* b2   = (const float*)d_in[6];
  const float* W3   = (const float*)d_in[7];
  const float* b3   = (const float*)d_in[8];
  const float* W4   = (const float*)d_in[9];
  const float* b4   = (const float*)d_in[10];
  const float* gamma = (const float*)d_in[11];
  const float* beta  = (const float*)d_in[12];
  const int* eidx   = (const int*)d_in[13];
  const int* batch  = (const int*)d_in[14];
  float* out = (float*)d_out;

  char* p = (char*)d_ws;
  size_t off = 0;
  auto take = [&](size_t n) { char* r = p + off; off = (off + n + 255) & ~(size_t)255; return r; };
  short* xbf = (short*)take((size_t)NN * ND * 2);
  short* w1p = (short*)take((size_t)384 * 512 * 2);
  short* w2p = (short*)take((size_t)512 * 128 * 2);
  short* w3p = (short*)take((size_t)448 * 1024 * 2);
  short* w4p = (short*)take((size_t)1024 * 256 * 2);
  unsigned int* cnt = (unsigned int*)take((size_t)NN * 4);
  int* elist = (int*)take((size_t)NN * MAXDEG * 4);
  unsigned short* aggbf = (unsigned short*)take((size_t)NN * ED * 2);
  unsigned short* ebuf = (unsigned short*)take((size_t)NE * ED * 2);

  const int* erow = eidx;
  const int* ecol = eidx + NE;

  hipMemsetAsync(cnt, 0, (size_t)NN * 4, stream);
  {
    const int total = J0 + J1 + J2 + J3 + J4 + J5;
    prep_kernel<<<(total + 255) / 256, 256, 0, stream>>>(x, xbf, W1, W2, W3, W4,
                                                         w1p, w2p, w3p, w4p,
                                                         ecol, cnt, elist);
  }
  edge_kernel<<<(NE + 127) / 128, 1024, 0, stream>>>(xbf, ea, w1p, b1, w2p, b2, erow, ebuf);
  agg_kernel<<<(NN + 3) / 4, 256, 0, stream>>>(ebuf, elist, cnt, aggbf);
  node_kernel<<<(NN + 63) / 64, 1024, 0, stream>>>(x, xbf, u, w3p, b3, w4p, b4,
                                                   gamma, beta, batch, aggbf, out);
}

// Round 17
// 649.443 us; speedup vs baseline: 2.3094x; 1.0135x over previous
//
#include <hip/hip_runtime.h>
#include <stdint.h>

#define NE 500000
#define NN 50000
#define ND 256
#define ED 128
#define GD 64
#define MAXDEG 64

typedef float f4v __attribute__((ext_vector_type(4)));
typedef short s8v __attribute__((ext_vector_type(8)));
typedef short s4v __attribute__((ext_vector_type(4)));

static __device__ __forceinline__ short f2bf(float f) {
  union { float f; uint32_t u; } v; v.f = f;
  uint32_t r = v.u + 0x7FFFu + ((v.u >> 16) & 1u);
  return (short)(r >> 16);
}
static __device__ __forceinline__ float bf2f(uint32_t u) {
  union { uint32_t u; float f; } v; v.u = u << 16; return v.f;
}

// ---- async global->LDS DMA, 16B per lane ----
static __device__ __forceinline__ void gload_lds16(const void* g, void* l) {
  __builtin_amdgcn_global_load_lds(
      (const __attribute__((address_space(1))) unsigned int*)g,
      (__attribute__((address_space(3))) unsigned int*)l,
      16, 0, 0);
}

// ---- pack W[K][C] fp32 -> bf16 MFMA fragment order [ks][c][kh][j] ----
static __device__ __forceinline__ void pack_one(const float* __restrict__ src,
                                                short* __restrict__ dst, int C, int idx) {
  int k = idx / C, c = idx - k * C;
  int ks = k >> 5, kh = (k >> 3) & 3, j = k & 7;
  dst[(((ks * C + c) * 4 + kh) << 3) + j] = f2bf(src[idx]);
}

// =======================================================================
// Fused prep: x->bf16 cvt | pack W1..W4 | build per-dest elist.
// =======================================================================
#define J0 3200000   // cvt: NN*ND/4 threads, 4 elems each
#define J1 196608    // w1p 384x512
#define J2 65536     // w2p 512x128
#define J3 458752    // w3p 448x1024
#define J4 262144    // w4p 1024x256
#define J5 500000    // build elist
__global__ void prep_kernel(const float* __restrict__ x, short* __restrict__ xbf,
                            const float* __restrict__ W1, const float* __restrict__ W2,
                            const float* __restrict__ W3, const float* __restrict__ W4,
                            short* __restrict__ w1p, short* __restrict__ w2p,
                            short* __restrict__ w3p, short* __restrict__ w4p,
                            const int* __restrict__ ecol, unsigned int* __restrict__ cnt,
                            int* __restrict__ elist) {
  int idx = blockIdx.x * blockDim.x + threadIdx.x;
  if (idx < J0) {
    int i = idx * 4;
    const float4 v = *(const float4*)(x + i);
    s4v o; o[0] = f2bf(v.x); o[1] = f2bf(v.y); o[2] = f2bf(v.z); o[3] = f2bf(v.w);
    *(s4v*)(xbf + i) = o;
    return;
  }
  idx -= J0;
  if (idx < J1) { pack_one(W1, w1p, 512, idx); return; }
  idx -= J1;
  if (idx < J2) { pack_one(W2, w2p, 128, idx); return; }
  idx -= J2;
  if (idx < J3) { pack_one(W3, w3p, 1024, idx); return; }
  idx -= J3;
  if (idx < J4) { pack_one(W4, w4p, 256, idx); return; }
  idx -= J4;
  if (idx < J5) {
    int c = ecol[idx];
    unsigned int slot = atomicAdd(&cnt[c], 1u);
    if (slot < MAXDEG) elist[c * MAXDEG + slot] = idx;
  }
}

// =======================================================================
// gather-mean (R16-benched): one wave per node, 4 edges/iter, 16B loads,
// shfl_xor(16,32) cross-group reduce.
// =======================================================================
__global__ void agg_kernel(const unsigned short* __restrict__ ebuf,
                           const int* __restrict__ elist,
                           const unsigned int* __restrict__ cnt,
                           unsigned short* __restrict__ aggbf) {
  int tid = threadIdx.x;
  int lane = tid & 63;
  int node = blockIdx.x * 4 + (tid >> 6);
  if (node >= NN) return;
  unsigned int deg = cnt[node];
  unsigned int jend = deg < MAXDEG ? deg : MAXDEG;
  const int jg = lane >> 4;        // 0..3
  const int ch = lane & 15;        // 16B chunk within row
  float a[8] = {0.f, 0.f, 0.f, 0.f, 0.f, 0.f, 0.f, 0.f};
  const int* el = elist + (size_t)node * MAXDEG;
  for (unsigned int j = jg; j < jend; j += 4) {
    int eid = el[j];
    s8v v = *(const s8v*)(ebuf + (size_t)eid * ED + ch * 8);
    #pragma unroll
    for (int i = 0; i < 8; ++i) a[i] += bf2f((uint32_t)(uint16_t)v[i]);
  }
  #pragma unroll
  for (int d = 16; d < 64; d <<= 1) {
    #pragma unroll
    for (int i = 0; i < 8; ++i) a[i] += __shfl_xor(a[i], d);
  }
  if (jg == 0) {
    float rc = 1.0f / (deg > 0 ? (float)deg : 1.0f);
    s8v o;
    #pragma unroll
    for (int i = 0; i < 8; ++i) o[i] = f2bf(a[i] * rc);
    *(s8v*)(aggbf + (size_t)node * ED + ch * 8) = o;
  }
}

// =======================================================================
// Edge kernel: R14 staging + FULL-H1 GEMM2 (3 barriers).
// After GEMM1 the X/E regions are dead -> full H1 [128][512] lives in
// Hb (half0, 64KB) + Xb (half1, 64KB). Sequence:
//   stage X(DMA)+E(VALU) | bar | GEMM1 K=384 | write half0->Hb |
//   bar (X reads done)   | write half1->Xb | bar | GEMM2 K=512 unsplit |
//   direct 8B stores.
// LESSONS FROZEN: (R9) no reg-held globals across MFMA (spill);
// (R15) no per-lane row-gathers feeding MFMA (uncoalesced);
// LDS staging = transaction shaping.
// =======================================================================
__launch_bounds__(1024, 4)
__global__ void edge_kernel(const short* __restrict__ xbf,
                            const float* __restrict__ edge_attr,
                            const short* __restrict__ w1p,
                            const float* __restrict__ b1,
                            const short* __restrict__ w2p,
                            const float* __restrict__ b2,
                            const int* __restrict__ erow,
                            unsigned short* __restrict__ ebuf) {
  __shared__ __align__(16) short smem[81920];       // 160KB
  char* const Xb = (char*)smem;                     // [128][256] bf16; later H1 half1
  char* const Eb = (char*)smem + 65536;             // [128][128] bf16
  char* const Hb = (char*)smem + 98304;             // H1 half0 [128][256], XOR swz
  const int tid = threadIdx.x;
  const int lane = tid & 63;
  const int w = tid >> 6;          // wave 0..15
  const int lh = lane >> 4;        // 0..3
  const int ll = lane & 15;        // 0..15
  const int e0 = blockIdx.x * 128;

  // ---- X: DMA xbf rows (1KB = 2 rows per inst, 4 insts per wave) ----
  {
    #pragma unroll
    for (int i = 0; i < 4; ++i) {
      int p = w * 4 + i;                     // row pair 0..63
      int row = 2 * p + (lane >> 5);
      int rid = erow[e0 + row];              // tail reads stay in eidx buffer
      int cg = (lane & 31) ^ (row & 7);      // source-swizzled octet
      gload_lds16(xbf + (size_t)rid * 256 + cg * 8, Xb + p * 1024);
    }
  }

  // ---- E: stage ea fp32 -> bf16, octet-swizzled (concurrent with DMA) ----
  #pragma unroll
  for (int it = 0; it < 2; ++it) {
    int id = tid + it * 1024;                // 2048 octets
    int row = id >> 4, oct = id & 15;
    s8v vals = {0, 0, 0, 0, 0, 0, 0, 0};
    if (e0 + row < NE) {
      const float* p = edge_attr + (size_t)(e0 + row) * ED + oct * 8;
      const float4 v0 = *(const float4*)(p);
      const float4 v1 = *(const float4*)(p + 4);
      vals[0] = f2bf(v0.x); vals[1] = f2bf(v0.y); vals[2] = f2bf(v0.z); vals[3] = f2bf(v0.w);
      vals[4] = f2bf(v1.x); vals[5] = f2bf(v1.y); vals[6] = f2bf(v1.z); vals[7] = f2bf(v1.w);
    }
    *(s8v*)(Eb + row * 256 + ((oct ^ (row & 7)) << 4)) = vals;
  }
  __syncthreads();   // barrier 1: DMA drained + E visible

  // ---- GEMM1 (swapped): acc1[n][mt]; n=0 -> cols 16w, n=1 -> 256+16w ----
  f4v acc1[2][8];
  #pragma unroll
  for (int n = 0; n < 2; ++n)
    #pragma unroll
    for (int m = 0; m < 8; ++m)
      acc1[n][m] = (f4v){0.f, 0.f, 0.f, 0.f};

  // ks 0..7: k<256 from X
  for (int ks = 0; ks < 8; ++ks) {
    s8v wf0 = *(const s8v*)(w1p + (((ks * 512 + w * 16 + ll) * 4 + lh) << 3));
    s8v wf1 = *(const s8v*)(w1p + (((ks * 512 + 256 + w * 16 + ll) * 4 + lh) << 3));
    #pragma unroll
    for (int mh = 0; mh < 2; ++mh) {
      s8v hf[4];
      #pragma unroll
      for (int m = 0; m < 4; ++m) {
        int row = 64 * mh + 16 * m + ll;
        int byte = row * 512 + (((ks * 4 + lh) ^ (row & 7)) << 4);
        hf[m] = *(const s8v*)(Xb + byte);
      }
      #pragma unroll
      for (int m = 0; m < 4; ++m) {
        acc1[0][4 * mh + m] = __builtin_amdgcn_mfma_f32_16x16x32_bf16(wf0, hf[m], acc1[0][4 * mh + m], 0, 0, 0);
        acc1[1][4 * mh + m] = __builtin_amdgcn_mfma_f32_16x16x32_bf16(wf1, hf[m], acc1[1][4 * mh + m], 0, 0, 0);
      }
    }
  }
  // ks 8..11: k>=256 from E
  for (int ks = 8; ks < 12; ++ks) {
    s8v wf0 = *(const s8v*)(w1p + (((ks * 512 + w * 16 + ll) * 4 + lh) << 3));
    s8v wf1 = *(const s8v*)(w1p + (((ks * 512 + 256 + w * 16 + ll) * 4 + lh) << 3));
    #pragma unroll
    for (int mh = 0; mh < 2; ++mh) {
      s8v hf[4];
      #pragma unroll
      for (int m = 0; m < 4; ++m) {
        int row = 64 * mh + 16 * m + ll;
        int byte = row * 256 + ((((ks - 8) * 4 + lh) ^ (row & 7)) << 4);
        hf[m] = *(const s8v*)(Eb + byte);
      }
      #pragma unroll
      for (int m = 0; m < 4; ++m) {
        acc1[0][4 * mh + m] = __builtin_amdgcn_mfma_f32_16x16x32_bf16(wf0, hf[m], acc1[0][4 * mh + m], 0, 0, 0);
        acc1[1][4 * mh + m] = __builtin_amdgcn_mfma_f32_16x16x32_bf16(wf1, hf[m], acc1[1][4 * mh + m], 0, 0, 0);
      }
    }
  }

  // ---- write H1 half0 -> Hb (Hb untouched; no barrier needed first) ----
  {
    int lcb = w * 16 + 4 * lh;
    const float4 bv = *(const float4*)(b1 + lcb);
    #pragma unroll
    for (int m = 0; m < 8; ++m) {
      int row = 16 * m + ll;
      s4v o;
      float v0 = acc1[0][m][0] + bv.x; o[0] = f2bf(v0 > 0.f ? v0 : 0.f);
      float v1 = acc1[0][m][1] + bv.y; o[1] = f2bf(v1 > 0.f ? v1 : 0.f);
      float v2 = acc1[0][m][2] + bv.z; o[2] = f2bf(v2 > 0.f ? v2 : 0.f);
      float v3 = acc1[0][m][3] + bv.w; o[3] = f2bf(v3 > 0.f ? v3 : 0.f);
      int byte = (row * 512 + lcb * 2) ^ ((row & 7) << 4);
      *(s4v*)(Hb + byte) = o;
    }
  }
  __syncthreads();   // barrier 2: all GEMM1 X-reads done -> Xb reusable

  // ---- write H1 half1 -> Xb (X data dead) ----
  {
    int lcb = w * 16 + 4 * lh;
    const float4 bv = *(const float4*)(b1 + 256 + lcb);
    #pragma unroll
    for (int m = 0; m < 8; ++m) {
      int row = 16 * m + ll;
      s4v o;
      float v0 = acc1[1][m][0] + bv.x; o[0] = f2bf(v0 > 0.f ? v0 : 0.f);
      float v1 = acc1[1][m][1] + bv.y; o[1] = f2bf(v1 > 0.f ? v1 : 0.f);
      float v2 = acc1[1][m][2] + bv.z; o[2] = f2bf(v2 > 0.f ? v2 : 0.f);
      float v3 = acc1[1][m][3] + bv.w; o[3] = f2bf(v3 > 0.f ? v3 : 0.f);
      int byte = (row * 512 + lcb * 2) ^ ((row & 7) << 4);
      *(s4v*)(Xb + byte) = o;
    }
  }
  __syncthreads();   // barrier 3: full H1 visible

  // ---- GEMM2 (swapped), full K=512 uninterrupted ----
  f4v acc2[4];
  #pragma unroll
  for (int m = 0; m < 4; ++m)
    acc2[m] = (f4v){0.f, 0.f, 0.f, 0.f};

  for (int ks = 0; ks < 8; ++ks) {
    s8v wf = *(const s8v*)(w2p + (((ks * 128 + (w & 7) * 16 + ll) * 4 + lh) << 3));
    #pragma unroll
    for (int m = 0; m < 4; ++m) {
      int row = 64 * (w >> 3) + 16 * m + ll;
      int byte = (row * 512 + ks * 64 + lh * 16) ^ ((row & 7) << 4);
      s8v hf = *(const s8v*)(Hb + byte);
      acc2[m] = __builtin_amdgcn_mfma_f32_16x16x32_bf16(wf, hf, acc2[m], 0, 0, 0);
    }
  }
  for (int ks = 8; ks < 16; ++ks) {
    s8v wf = *(const s8v*)(w2p + (((ks * 128 + (w & 7) * 16 + ll) * 4 + lh) << 3));
    #pragma unroll
    for (int m = 0; m < 4; ++m) {
      int row = 64 * (w >> 3) + 16 * m + ll;
      int byte = (row * 512 + (ks - 8) * 64 + lh * 16) ^ ((row & 7) << 4);
      s8v hf = *(const s8v*)(Xb + byte);
      acc2[m] = __builtin_amdgcn_mfma_f32_16x16x32_bf16(wf, hf, acc2[m], 0, 0, 0);
    }
  }

  // ---- epilogue: direct 8B stores ----
  {
    int cb = (w & 7) * 16 + 4 * lh;
    const float4 bv = *(const float4*)(b2 + cb);
    #pragma unroll
    for (int m = 0; m < 4; ++m) {
      int row = 64 * (w >> 3) + 16 * m + ll;
      int e = e0 + row;
      if (e < NE) {
        s4v o;
        o[0] = f2bf(acc2[m][0] + bv.x);
        o[1] = f2bf(acc2[m][1] + bv.y);
        o[2] = f2bf(acc2[m][2] + bv.z);
        o[3] = f2bf(acc2[m][3] + bv.w);
        *(s4v*)(ebuf + (size_t)e * ED + cb) = o;
      }
    }
  }
}

// =======================================================================
// Node kernel: unchanged (R10/R16-benched, 16 waves).
// =======================================================================
__launch_bounds__(1024, 4)
__global__ void node_kernel(const float* __restrict__ x,
                            const short* __restrict__ xbf,
                            const float* __restrict__ u,
                            const short* __restrict__ w3p,
                            const float* __restrict__ b3,
                            const short* __restrict__ w4p,
                            const float* __restrict__ b4,
                            const float* __restrict__ gamma,
                            const float* __restrict__ beta,
                            const int* __restrict__ batch,
                            const unsigned short* __restrict__ aggbf,
                            float* __restrict__ out) {
  __shared__ __align__(16) short smem[64 * 1024];
  const int tid = threadIdx.x;
  const int lane = tid & 63;
  const int w = tid >> 6;
  const int lh = lane >> 4;
  const int ll = lane & 15;
  const int n0 = blockIdx.x * 64;

  #pragma unroll
  for (int it = 0; it < 4; ++it) {
    int ch = tid + it * 1024;
    if (ch < 3584) {
      int rr = ch / 56;
      int cc = (ch - rr * 56) * 8;
      s8v vals = {0, 0, 0, 0, 0, 0, 0, 0};
      int node = n0 + rr;
      if (node < NN) {
        if (cc < 256) {
          vals = *(const s8v*)(xbf + (size_t)node * ND + cc);
        } else if (cc < 384) {
          vals = *(const s8v*)(aggbf + (size_t)node * ED + (cc - 256));
        } else {
          const float* up = u + (size_t)batch[node] * GD + (cc - 384);
          const float4 v0 = *(const float4*)(up);
          const float4 v1 = *(const float4*)(up + 4);
          vals[0] = f2bf(v0.x); vals[1] = f2bf(v0.y); vals[2] = f2bf(v0.z); vals[3] = f2bf(v0.w);
          vals[4] = f2bf(v1.x); vals[5] = f2bf(v1.y); vals[6] = f2bf(v1.z); vals[7] = f2bf(v1.w);
        }
      }
      int byte = (rr * 896 + cc * 2) ^ ((rr & 7) << 4);
      *(s8v*)((char*)smem + byte) = vals;
    }
  }
  __syncthreads();

  f4v acc3[4][4];
  #pragma unroll
  for (int n = 0; n < 4; ++n)
    #pragma unroll
    for (int m = 0; m < 4; ++m)
      acc3[n][m] = (f4v){0.f, 0.f, 0.f, 0.f};

  for (int ks = 0; ks < 14; ++ks) {
    s8v af[4];
    #pragma unroll
    for (int m = 0; m < 4; ++m) {
      int row = 16 * m + ll;
      int byte = (row * 896 + ks * 64 + lh * 16) ^ ((row & 7) << 4);
      af[m] = *(const s8v*)((const char*)smem + byte);
    }
    #pragma unroll
    for (int n = 0; n < 4; ++n) {
      s8v wf = *(const s8v*)(w3p + (((ks * 1024 + w * 64 + 16 * n + ll) * 4 + lh) << 3));
      #pragma unroll
      for (int m = 0; m < 4; ++m)
        acc3[n][m] = __builtin_amdgcn_mfma_f32_16x16x32_bf16(wf, af[m], acc3[n][m], 0, 0, 0);
    }
  }
  __syncthreads();

  #pragma unroll
  for (int n = 0; n < 4; ++n) {
    int cb = w * 64 + 16 * n + 4 * lh;
    const float4 bv = *(const float4*)(b3 + cb);
    #pragma unroll
    for (int m = 0; m < 4; ++m) {
      int row = 16 * m + ll;
      s4v o;
      float v0 = acc3[n][m][0] + bv.x; o[0] = f2bf(v0 > 0.f ? v0 : 0.f);
      float v1 = acc3[n][m][1] + bv.y; o[1] = f2bf(v1 > 0.f ? v1 : 0.f);
      float v2 = acc3[n][m][2] + bv.z; o[2] = f2bf(v2 > 0.f ? v2 : 0.f);
      float v3 = acc3[n][m][3] + bv.w; o[3] = f2bf(v3 > 0.f ? v3 : 0.f);
      int byte = (row * 2048 + cb * 2) ^ ((row & 7) << 4);
      *(s4v*)((char*)smem + byte) = o;
    }
  }
  __syncthreads();

  f4v acc4[4];
  #pragma unroll
  for (int m = 0; m < 4; ++m)
    acc4[m] = (f4v){0.f, 0.f, 0.f, 0.f};

  for (int ks = 0; ks < 32; ++ks) {
    s8v wf = *(const s8v*)(w4p + (((ks * 256 + w * 16 + ll) * 4 + lh) << 3));
    #pragma unroll
    for (int m = 0; m < 4; ++m) {
      int row = 16 * m + ll;
      int byte = (row * 2048 + ks * 64 + lh * 16) ^ ((row & 7) << 4);
      s8v hf = *(const s8v*)((const char*)smem + byte);
      acc4[m] = __builtin_amdgcn_mfma_f32_16x16x32_bf16(wf, hf, acc4[m], 0, 0, 0);
    }
  }
  __syncthreads();

  float* yb = (float*)smem;
  {
    int cb = w * 16 + 4 * lh;
    const float4 bv = *(const float4*)(b4 + cb);
    #pragma unroll
    for (int m = 0; m < 4; ++m) {
      int row = 16 * m + ll;
      int node = n0 + row;
      float4 xv = {0.f, 0.f, 0.f, 0.f};
      if (node < NN) xv = *(const float4*)(x + (size_t)node * ND + cb);
      f4v o;
      o[0] = acc4[m][0] + bv.x + xv.x;
      o[1] = acc4[m][1] + bv.y + xv.y;
      o[2] = acc4[m][2] + bv.z + xv.z;
      o[3] = acc4[m][3] + bv.w + xv.w;
      *(f4v*)(yb + row * 260 + cb) = o;
    }
  }
  __syncthreads();

  {
    int row = tid >> 4, sub = tid & 15;
    int node = n0 + row;
    float v[16];
    float sum = 0.f, ssq = 0.f;
    #pragma unroll
    for (int i = 0; i < 4; ++i) {
      const float4 t = *(const float4*)(yb + row * 260 + (i * 16 + sub) * 4);
      v[i * 4 + 0] = t.x; v[i * 4 + 1] = t.y; v[i * 4 + 2] = t.z; v[i * 4 + 3] = t.w;
      sum += t.x + t.y + t.z + t.w;
      ssq += t.x * t.x + t.y * t.y + t.z * t.z + t.w * t.w;
    }
    #pragma unroll
    for (int d = 1; d < 16; d <<= 1) {
      sum += __shfl_xor(sum, d);
      ssq += __shfl_xor(ssq, d);
    }
    float mu = sum * (1.f / 256.f);
    float var = ssq * (1.f / 256.f) - mu * mu;
    float rstd = rsqrtf(var + 1e-5f);
    if (node < NN) {
      #pragma unroll
      for (int i = 0; i < 4; ++i) {
        int c = (i * 16 + sub) * 4;
        const float4 g = *(const float4*)(gamma + c);
        const float4 be = *(const float4*)(beta + c);
        float4 o;
        o.x = (v[i * 4 + 0] - mu) * rstd * g.x + be.x;
        o.y = (v[i * 4 + 1] - mu) * rstd * g.y + be.y;
        o.z = (v[i * 4 + 2] - mu) * rstd * g.z + be.z;
        o.w = (v[i * 4 + 3] - mu) * rstd * g.w + be.w;
        *(float4*)(out + (size_t)node * ND + c) = o;
      }
    }
  }
}

extern "C" void kernel_launch(void* const* d_in, const int* in_sizes, int n_in,
                              void* d_out, int out_size, void* d_ws, size_t ws_size,
                              hipStream_t stream) {
  const float* x    = (const float*)d_in[0];
  const float* ea   = (const float*)d_in[1];
  const float* u    = (const float*)d_in[2];
  const float* W1   = (const float*)d_in[3];
  const float* b1   = (const float*)d_in[4];
  const float* W2   = (const float*)d_in[5];
  const float* b2   = (const float*)d_in[6];
  const float* W3   = (const float*)d_in[7];
  const float* b3   = (const float*)d_in[8];
  const float* W4   = (const float*)d_in[9];
  const float* b4   = (const float*)d_in[10];
  const float* gamma = (const float*)d_in[11];
  const float* beta  = (const float*)d_in[12];
  const int* eidx   = (const int*)d_in[13];
  const int* batch  = (const int*)d_in[14];
  float* out = (float*)d_out;

  char* p = (char*)d_ws;
  size_t off = 0;
  auto take = [&](size_t n) { char* r = p + off; off = (off + n + 255) & ~(size_t)255; return r; };
  short* xbf = (short*)take((size_t)NN * ND * 2);
  short* w1p = (short*)take((size_t)384 * 512 * 2);
  short* w2p = (short*)take((size_t)512 * 128 * 2);
  short* w3p = (short*)take((size_t)448 * 1024 * 2);
  short* w4p = (short*)take((size_t)1024 * 256 * 2);
  unsigned int* cnt = (unsigned int*)take((size_t)NN * 4);
  int* elist = (int*)take((size_t)NN * MAXDEG * 4);
  unsigned short* aggbf = (unsigned short*)take((size_t)NN * ED * 2);
  unsigned short* ebuf = (unsigned short*)take((size_t)NE * ED * 2);

  const int* erow = eidx;
  const int* ecol = eidx + NE;

  hipMemsetAsync(cnt, 0, (size_t)NN * 4, stream);
  {
    const int total = J0 + J1 + J2 + J3 + J4 + J5;
    prep_kernel<<<(total + 255) / 256, 256, 0, stream>>>(x, xbf, W1, W2, W3, W4,
                                                         w1p, w2p, w3p, w4p,
                                                         ecol, cnt, elist);
  }
  edge_kernel<<<(NE + 127) / 128, 1024, 0, stream>>>(xbf, ea, w1p, b1, w2p, b2, erow, ebuf);
  agg_kernel<<<(NN + 3) / 4, 256, 0, stream>>>(ebuf, elist, cnt, aggbf);
  node_kernel<<<(NN + 63) / 64, 1024, 0, stream>>>(x, xbf, u, w3p, b3, w4p, b4,
                                                   gamma, beta, batch, aggbf, out);
}

// Round 18
// 583.481 us; speedup vs baseline: 2.5704x; 1.1131x over previous
//
#include <hip/hip_runtime.h>
#include <stdint.h>

#define NE 500000
#define NN 50000
#define ND 256
#define ED 128
#define GD 64
#define MAXDEG 64

typedef float f4v __attribute__((ext_vector_type(4)));
typedef short s8v __attribute__((ext_vector_type(8)));
typedef short s4v __attribute__((ext_vector_type(4)));

static __device__ __forceinline__ short f2bf(float f) {
  union { float f; uint32_t u; } v; v.f = f;
  uint32_t r = v.u + 0x7FFFu + ((v.u >> 16) & 1u);
  return (short)(r >> 16);
}
static __device__ __forceinline__ float bf2f(uint32_t u) {
  union { uint32_t u; float f; } v; v.u = u << 16; return v.f;
}

// ---- async global->LDS DMA, 16B per lane ----
static __device__ __forceinline__ void gload_lds16(const void* g, void* l) {
  __builtin_amdgcn_global_load_lds(
      (const __attribute__((address_space(1))) unsigned int*)g,
      (__attribute__((address_space(3))) unsigned int*)l,
      16, 0, 0);
}

// ---- pack W[K][C] fp32 -> bf16 MFMA fragment order [ks][c][kh][j] ----
static __device__ __forceinline__ void pack_one(const float* __restrict__ src,
                                                short* __restrict__ dst, int C, int idx) {
  int k = idx / C, c = idx - k * C;
  int ks = k >> 5, kh = (k >> 3) & 3, j = k & 7;
  dst[(((ks * C + c) * 4 + kh) << 3) + j] = f2bf(src[idx]);
}

// =======================================================================
// Fused prep. elist-build placed FIRST so its atomic/scatter latency
// starts earliest and hides under the cvt/pack bulk.
// =======================================================================
#define J5 500000    // build elist (first)
#define J0 3200000   // cvt: NN*ND/4 threads, 4 elems each
#define J1 196608    // w1p 384x512
#define J2 65536     // w2p 512x128
#define J3 458752    // w3p 448x1024
#define J4 262144    // w4p 1024x256
__global__ void prep_kernel(const float* __restrict__ x, short* __restrict__ xbf,
                            const float* __restrict__ W1, const float* __restrict__ W2,
                            const float* __restrict__ W3, const float* __restrict__ W4,
                            short* __restrict__ w1p, short* __restrict__ w2p,
                            short* __restrict__ w3p, short* __restrict__ w4p,
                            const int* __restrict__ ecol, unsigned int* __restrict__ cnt,
                            int* __restrict__ elist) {
  int idx = blockIdx.x * blockDim.x + threadIdx.x;
  if (idx < J5) {
    int c = ecol[idx];
    unsigned int slot = atomicAdd(&cnt[c], 1u);
    if (slot < MAXDEG) elist[c * MAXDEG + slot] = idx;
    return;
  }
  idx -= J5;
  if (idx < J0) {
    int i = idx * 4;
    const float4 v = *(const float4*)(x + i);
    s4v o; o[0] = f2bf(v.x); o[1] = f2bf(v.y); o[2] = f2bf(v.z); o[3] = f2bf(v.w);
    *(s4v*)(xbf + i) = o;
    return;
  }
  idx -= J0;
  if (idx < J1) { pack_one(W1, w1p, 512, idx); return; }
  idx -= J1;
  if (idx < J2) { pack_one(W2, w2p, 128, idx); return; }
  idx -= J2;
  if (idx < J3) { pack_one(W3, w3p, 1024, idx); return; }
  idx -= J3;
  if (idx < J4) { pack_one(W4, w4p, 256, idx); return; }
}

// =======================================================================
// gather-mean (R16-benched): one wave per node, 4 edges/iter, 16B loads,
// shfl_xor(16,32) cross-group reduce.
// =======================================================================
__global__ void agg_kernel(const unsigned short* __restrict__ ebuf,
                           const int* __restrict__ elist,
                           const unsigned int* __restrict__ cnt,
                           unsigned short* __restrict__ aggbf) {
  int tid = threadIdx.x;
  int lane = tid & 63;
  int node = blockIdx.x * 4 + (tid >> 6);
  if (node >= NN) return;
  unsigned int deg = cnt[node];
  unsigned int jend = deg < MAXDEG ? deg : MAXDEG;
  const int jg = lane >> 4;        // 0..3
  const int ch = lane & 15;        // 16B chunk within row
  float a[8] = {0.f, 0.f, 0.f, 0.f, 0.f, 0.f, 0.f, 0.f};
  const int* el = elist + (size_t)node * MAXDEG;
  for (unsigned int j = jg; j < jend; j += 4) {
    int eid = el[j];
    s8v v = *(const s8v*)(ebuf + (size_t)eid * ED + ch * 8);
    #pragma unroll
    for (int i = 0; i < 8; ++i) a[i] += bf2f((uint32_t)(uint16_t)v[i]);
  }
  #pragma unroll
  for (int d = 16; d < 64; d <<= 1) {
    #pragma unroll
    for (int i = 0; i < 8; ++i) a[i] += __shfl_xor(a[i], d);
  }
  if (jg == 0) {
    float rc = 1.0f / (deg > 0 ? (float)deg : 1.0f);
    s8v o;
    #pragma unroll
    for (int i = 0; i < 8; ++i) o[i] = f2bf(a[i] * rc);
    *(s8v*)(aggbf + (size_t)node * ED + ch * 8) = o;
  }
}

// =======================================================================
// Edge kernel: EXACT R17-benched version (388us, MfmaUtil 29.6, clean).
// LESSONS FROZEN: (R9) no reg-held globals across MFMA (spill);
// (R15) no per-lane row-gathers feeding MFMA (uncoalesced);
// LDS staging = transaction shaping.
// =======================================================================
__launch_bounds__(1024, 4)
__global__ void edge_kernel(const short* __restrict__ xbf,
                            const float* __restrict__ edge_attr,
                            const short* __restrict__ w1p,
                            const float* __restrict__ b1,
                            const short* __restrict__ w2p,
                            const float* __restrict__ b2,
                            const int* __restrict__ erow,
                            unsigned short* __restrict__ ebuf) {
  __shared__ __align__(16) short smem[81920];       // 160KB
  char* const Xb = (char*)smem;                     // [128][256] bf16; later H1 half1
  char* const Eb = (char*)smem + 65536;             // [128][128] bf16
  char* const Hb = (char*)smem + 98304;             // H1 half0 [128][256], XOR swz
  const int tid = threadIdx.x;
  const int lane = tid & 63;
  const int w = tid >> 6;          // wave 0..15
  const int lh = lane >> 4;        // 0..3
  const int ll = lane & 15;        // 0..15
  const int e0 = blockIdx.x * 128;

  {
    #pragma unroll
    for (int i = 0; i < 4; ++i) {
      int p = w * 4 + i;                     // row pair 0..63
      int row = 2 * p + (lane >> 5);
      int rid = erow[e0 + row];              // tail reads stay in eidx buffer
      int cg = (lane & 31) ^ (row & 7);      // source-swizzled octet
      gload_lds16(xbf + (size_t)rid * 256 + cg * 8, Xb + p * 1024);
    }
  }

  #pragma unroll
  for (int it = 0; it < 2; ++it) {
    int id = tid + it * 1024;                // 2048 octets
    int row = id >> 4, oct = id & 15;
    s8v vals = {0, 0, 0, 0, 0, 0, 0, 0};
    if (e0 + row < NE) {
      const float* p = edge_attr + (size_t)(e0 + row) * ED + oct * 8;
      const float4 v0 = *(const float4*)(p);
      const float4 v1 = *(const float4*)(p + 4);
      vals[0] = f2bf(v0.x); vals[1] = f2bf(v0.y); vals[2] = f2bf(v0.z); vals[3] = f2bf(v0.w);
      vals[4] = f2bf(v1.x); vals[5] = f2bf(v1.y); vals[6] = f2bf(v1.z); vals[7] = f2bf(v1.w);
    }
    *(s8v*)(Eb + row * 256 + ((oct ^ (row & 7)) << 4)) = vals;
  }
  __syncthreads();   // barrier 1: DMA drained + E visible

  f4v acc1[2][8];
  #pragma unroll
  for (int n = 0; n < 2; ++n)
    #pragma unroll
    for (int m = 0; m < 8; ++m)
      acc1[n][m] = (f4v){0.f, 0.f, 0.f, 0.f};

  for (int ks = 0; ks < 8; ++ks) {
    s8v wf0 = *(const s8v*)(w1p + (((ks * 512 + w * 16 + ll) * 4 + lh) << 3));
    s8v wf1 = *(const s8v*)(w1p + (((ks * 512 + 256 + w * 16 + ll) * 4 + lh) << 3));
    #pragma unroll
    for (int mh = 0; mh < 2; ++mh) {
      s8v hf[4];
      #pragma unroll
      for (int m = 0; m < 4; ++m) {
        int row = 64 * mh + 16 * m + ll;
        int byte = row * 512 + (((ks * 4 + lh) ^ (row & 7)) << 4);
        hf[m] = *(const s8v*)(Xb + byte);
      }
      #pragma unroll
      for (int m = 0; m < 4; ++m) {
        acc1[0][4 * mh + m] = __builtin_amdgcn_mfma_f32_16x16x32_bf16(wf0, hf[m], acc1[0][4 * mh + m], 0, 0, 0);
        acc1[1][4 * mh + m] = __builtin_amdgcn_mfma_f32_16x16x32_bf16(wf1, hf[m], acc1[1][4 * mh + m], 0, 0, 0);
      }
    }
  }
  for (int ks = 8; ks < 12; ++ks) {
    s8v wf0 = *(const s8v*)(w1p + (((ks * 512 + w * 16 + ll) * 4 + lh) << 3));
    s8v wf1 = *(const s8v*)(w1p + (((ks * 512 + 256 + w * 16 + ll) * 4 + lh) << 3));
    #pragma unroll
    for (int mh = 0; mh < 2; ++mh) {
      s8v hf[4];
      #pragma unroll
      for (int m = 0; m < 4; ++m) {
        int row = 64 * mh + 16 * m + ll;
        int byte = row * 256 + ((((ks - 8) * 4 + lh) ^ (row & 7)) << 4);
        hf[m] = *(const s8v*)(Eb + byte);
      }
      #pragma unroll
      for (int m = 0; m < 4; ++m) {
        acc1[0][4 * mh + m] = __builtin_amdgcn_mfma_f32_16x16x32_bf16(wf0, hf[m], acc1[0][4 * mh + m], 0, 0, 0);
        acc1[1][4 * mh + m] = __builtin_amdgcn_mfma_f32_16x16x32_bf16(wf1, hf[m], acc1[1][4 * mh + m], 0, 0, 0);
      }
    }
  }

  {
    int lcb = w * 16 + 4 * lh;
    const float4 bv = *(const float4*)(b1 + lcb);
    #pragma unroll
    for (int m = 0; m < 8; ++m) {
      int row = 16 * m + ll;
      s4v o;
      float v0 = acc1[0][m][0] + bv.x; o[0] = f2bf(v0 > 0.f ? v0 : 0.f);
      float v1 = acc1[0][m][1] + bv.y; o[1] = f2bf(v1 > 0.f ? v1 : 0.f);
      float v2 = acc1[0][m][2] + bv.z; o[2] = f2bf(v2 > 0.f ? v2 : 0.f);
      float v3 = acc1[0][m][3] + bv.w; o[3] = f2bf(v3 > 0.f ? v3 : 0.f);
      int byte = (row * 512 + lcb * 2) ^ ((row & 7) << 4);
      *(s4v*)(Hb + byte) = o;
    }
  }
  __syncthreads();   // barrier 2: all GEMM1 X-reads done -> Xb reusable

  {
    int lcb = w * 16 + 4 * lh;
    const float4 bv = *(const float4*)(b1 + 256 + lcb);
    #pragma unroll
    for (int m = 0; m < 8; ++m) {
      int row = 16 * m + ll;
      s4v o;
      float v0 = acc1[1][m][0] + bv.x; o[0] = f2bf(v0 > 0.f ? v0 : 0.f);
      float v1 = acc1[1][m][1] + bv.y; o[1] = f2bf(v1 > 0.f ? v1 : 0.f);
      float v2 = acc1[1][m][2] + bv.z; o[2] = f2bf(v2 > 0.f ? v2 : 0.f);
      float v3 = acc1[1][m][3] + bv.w; o[3] = f2bf(v3 > 0.f ? v3 : 0.f);
      int byte = (row * 512 + lcb * 2) ^ ((row & 7) << 4);
      *(s4v*)(Xb + byte) = o;
    }
  }
  __syncthreads();   // barrier 3: full H1 visible

  f4v acc2[4];
  #pragma unroll
  for (int m = 0; m < 4; ++m)
    acc2[m] = (f4v){0.f, 0.f, 0.f, 0.f};

  for (int ks = 0; ks < 8; ++ks) {
    s8v wf = *(const s8v*)(w2p + (((ks * 128 + (w & 7) * 16 + ll) * 4 + lh) << 3));
    #pragma unroll
    for (int m = 0; m < 4; ++m) {
      int row = 64 * (w >> 3) + 16 * m + ll;
      int byte = (row * 512 + ks * 64 + lh * 16) ^ ((row & 7) << 4);
      s8v hf = *(const s8v*)(Hb + byte);
      acc2[m] = __builtin_amdgcn_mfma_f32_16x16x32_bf16(wf, hf, acc2[m], 0, 0, 0);
    }
  }
  for (int ks = 8; ks < 16; ++ks) {
    s8v wf = *(const s8v*)(w2p + (((ks * 128 + (w & 7) * 16 + ll) * 4 + lh) << 3));
    #pragma unroll
    for (int m = 0; m < 4; ++m) {
      int row = 64 * (w >> 3) + 16 * m + ll;
      int byte = (row * 512 + (ks - 8) * 64 + lh * 16) ^ ((row & 7) << 4);
      s8v hf = *(const s8v*)(Xb + byte);
      acc2[m] = __builtin_amdgcn_mfma_f32_16x16x32_bf16(wf, hf, acc2[m], 0, 0, 0);
    }
  }

  {
    int cb = (w & 7) * 16 + 4 * lh;
    const float4 bv = *(const float4*)(b2 + cb);
    #pragma unroll
    for (int m = 0; m < 4; ++m) {
      int row = 64 * (w >> 3) + 16 * m + ll;
      int e = e0 + row;
      if (e < NE) {
        s4v o;
        o[0] = f2bf(acc2[m][0] + bv.x);
        o[1] = f2bf(acc2[m][1] + bv.y);
        o[2] = f2bf(acc2[m][2] + bv.z);
        o[3] = f2bf(acc2[m][3] + bv.w);
        *(s4v*)(ebuf + (size_t)e * ED + cb) = o;
      }
    }
  }
}

// =======================================================================
// Node kernel v2: edge-R17 structure ported.
//  - A3 split staging: x-part [64][256]bf16 (32KB) via gload_lds with
//    source-swizzled octets; agg [64][128] (16KB, bf16 copy) + u [64][64]
//    (8KB, fp32->bf16) staged by VALU concurrently. 1 barrier.
//  - GEMM3 K=448 reads Xn/An/Un regions (proven fragment pattern).
//  - H3 halves [64][512] (64KB each): h0 -> dedicated region (waves 0-7,
//    no pre-barrier); bar; h1 -> dead stage region (waves 8-15) WHILE
//    waves 0-7 run GEMM4 on h0; bar; GEMM4 on h1.
//  - y/LN unchanged (y aliases h1 region after its reads drain).
// LDS: [0,64K) stage(56K)+pad -> h1; [64K,128K) h0. Total 128KB.
// =======================================================================
__launch_bounds__(1024, 4)
__global__ void node_kernel(const float* __restrict__ x,
                            const short* __restrict__ xbf,
                            const float* __restrict__ u,
                            const short* __restrict__ w3p,
                            const float* __restrict__ b3,
                            const short* __restrict__ w4p,
                            const float* __restrict__ b4,
                            const float* __restrict__ gamma,
                            const float* __restrict__ beta,
                            const int* __restrict__ batch,
                            const unsigned short* __restrict__ aggbf,
                            float* __restrict__ out) {
  __shared__ __align__(16) short smem[65536];       // 128KB
  char* const Xn = (char*)smem;                     // [64][256] bf16, 512B rows
  char* const An = (char*)smem + 32768;             // [64][128] bf16, 256B rows
  char* const Un = (char*)smem + 49152;             // [64][64]  bf16, 128B rows
  char* const H1r = (char*)smem;                    // H3 half1 (over stage)
  char* const H0r = (char*)smem + 65536;            // H3 half0
  const int tid = threadIdx.x;
  const int lane = tid & 63;
  const int w = tid >> 6;          // 0..15
  const int lh = lane >> 4;        // 0..3
  const int ll = lane & 15;        // 0..15
  const int n0 = blockIdx.x * 64;

  // ---- X: DMA xbf rows (1KB = 2 rows/inst, 2 insts per wave) ----
  {
    #pragma unroll
    for (int i = 0; i < 2; ++i) {
      int p = w * 2 + i;                     // row pair 0..31
      int row = 2 * p + (lane >> 5);
      int node = n0 + row; if (node >= NN) node = NN - 1;
      int cg = (lane & 31) ^ (row & 7);
      gload_lds16(xbf + (size_t)node * 256 + cg * 8, Xn + p * 1024);
    }
  }
  // ---- An: agg bf16 copy (1024 octets); Un: u fp32->bf16 (512 octets) ----
  {
    int row = tid >> 4, oct = tid & 15;      // An: all 1024 threads
    s8v v = {0, 0, 0, 0, 0, 0, 0, 0};
    int node = n0 + row;
    if (node < NN) v = *(const s8v*)(aggbf + (size_t)node * ED + oct * 8);
    *(s8v*)(An + row * 256 + ((oct ^ (row & 7)) << 4)) = v;
  }
  if (tid < 512) {
    int row = tid >> 3, oct = tid & 7;
    s8v v = {0, 0, 0, 0, 0, 0, 0, 0};
    int node = n0 + row;
    if (node < NN) {
      const float* up = u + (size_t)batch[node] * GD + oct * 8;
      const float4 v0 = *(const float4*)(up);
      const float4 v1 = *(const float4*)(up + 4);
      v[0] = f2bf(v0.x); v[1] = f2bf(v0.y); v[2] = f2bf(v0.z); v[3] = f2bf(v0.w);
      v[4] = f2bf(v1.x); v[5] = f2bf(v1.y); v[6] = f2bf(v1.z); v[7] = f2bf(v1.w);
    }
    *(s8v*)(Un + row * 128 + ((oct ^ (row & 7)) << 4)) = v;
  }
  __syncthreads();   // barrier 1: DMA drained + An/Un visible

  // ---- GEMM3 (swapped): wave w -> cols [w*64,+64), K=448 ----
  f4v acc3[4][4];
  #pragma unroll
  for (int n = 0; n < 4; ++n)
    #pragma unroll
    for (int m = 0; m < 4; ++m)
      acc3[n][m] = (f4v){0.f, 0.f, 0.f, 0.f};

  for (int ks = 0; ks < 14; ++ks) {
    s8v af[4];
    #pragma unroll
    for (int m = 0; m < 4; ++m) {
      int row = 16 * m + ll;
      int byte;
      if (ks < 8)       byte = row * 512 + (((ks * 4 + lh) ^ (row & 7)) << 4);
      else if (ks < 12) byte = row * 256 + ((((ks - 8) * 4 + lh) ^ (row & 7)) << 4);
      else              byte = row * 128 + ((((ks - 12) * 4 + lh) ^ (row & 7)) << 4);
      const char* base = (ks < 8) ? Xn : (ks < 12) ? An : Un;
      af[m] = *(const s8v*)(base + byte);
    }
    #pragma unroll
    for (int n = 0; n < 4; ++n) {
      s8v wf = *(const s8v*)(w3p + (((ks * 1024 + w * 64 + 16 * n + ll) * 4 + lh) << 3));
      #pragma unroll
      for (int m = 0; m < 4; ++m)
        acc3[n][m] = __builtin_amdgcn_mfma_f32_16x16x32_bf16(wf, af[m], acc3[n][m], 0, 0, 0);
    }
  }

  // ---- write h0 (waves 0-7: cols [64w, 64w+64) < 512), region fresh ----
  if (w < 8) {
    #pragma unroll
    for (int n = 0; n < 4; ++n) {
      int lc = w * 64 + 16 * n + 4 * lh;          // local col in [0,512)
      const float4 bv = *(const float4*)(b3 + lc);
      #pragma unroll
      for (int m = 0; m < 4; ++m) {
        int row = 16 * m + ll;
        s4v o;
        float v0 = acc3[n][m][0] + bv.x; o[0] = f2bf(v0 > 0.f ? v0 : 0.f);
        float v1 = acc3[n][m][1] + bv.y; o[1] = f2bf(v1 > 0.f ? v1 : 0.f);
        float v2 = acc3[n][m][2] + bv.z; o[2] = f2bf(v2 > 0.f ? v2 : 0.f);
        float v3 = acc3[n][m][3] + bv.w; o[3] = f2bf(v3 > 0.f ? v3 : 0.f);
        int byte = (row * 1024 + lc * 2) ^ ((row & 7) << 4);
        *(s4v*)(H0r + byte) = o;
      }
    }
  }
  __syncthreads();   // barrier 2: stage reads done (h1 region free) + h0 visible

  // ---- waves 8-15: write h1 over stage region; then all waves GEMM4-h0 ----
  if (w >= 8) {
    #pragma unroll
    for (int n = 0; n < 4; ++n) {
      int lc = (w - 8) * 64 + 16 * n + 4 * lh;    // local col in [0,512)
      const float4 bv = *(const float4*)(b3 + 512 + lc);
      #pragma unroll
      for (int m = 0; m < 4; ++m) {
        int row = 16 * m + ll;
        s4v o;
        float v0 = acc3[n][m][0] + bv.x; o[0] = f2bf(v0 > 0.f ? v0 : 0.f);
        float v1 = acc3[n][m][1] + bv.y; o[1] = f2bf(v1 > 0.f ? v1 : 0.f);
        float v2 = acc3[n][m][2] + bv.z; o[2] = f2bf(v2 > 0.f ? v2 : 0.f);
        float v3 = acc3[n][m][3] + bv.w; o[3] = f2bf(v3 > 0.f ? v3 : 0.f);
        int byte = (row * 1024 + lc * 2) ^ ((row & 7) << 4);
        *(s4v*)(H1r + byte) = o;
      }
    }
  }

  f4v acc4[4];
  #pragma unroll
  for (int m = 0; m < 4; ++m)
    acc4[m] = (f4v){0.f, 0.f, 0.f, 0.f};

  // GEMM4 on h0 (K 0..511): overlaps waves 8-15's h1 writes
  for (int ks = 0; ks < 16; ++ks) {
    s8v wf = *(const s8v*)(w4p + (((ks * 256 + w * 16 + ll) * 4 + lh) << 3));
    #pragma unroll
    for (int m = 0; m < 4; ++m) {
      int row = 16 * m + ll;
      int byte = (row * 1024 + ks * 64 + lh * 16) ^ ((row & 7) << 4);
      s8v hf = *(const s8v*)(H0r + byte);
      acc4[m] = __builtin_amdgcn_mfma_f32_16x16x32_bf16(wf, hf, acc4[m], 0, 0, 0);
    }
  }
  __syncthreads();   // barrier 3: h1 visible

  // GEMM4 on h1 (K 512..1023)
  for (int ks = 16; ks < 32; ++ks) {
    s8v wf = *(const s8v*)(w4p + (((ks * 256 + w * 16 + ll) * 4 + lh) << 3));
    #pragma unroll
    for (int m = 0; m < 4; ++m) {
      int row = 16 * m + ll;
      int byte = (row * 1024 + (ks - 16) * 64 + lh * 16) ^ ((row & 7) << 4);
      s8v hf = *(const s8v*)(H1r + byte);
      acc4[m] = __builtin_amdgcn_mfma_f32_16x16x32_bf16(wf, hf, acc4[m], 0, 0, 0);
    }
  }
  __syncthreads();   // barrier 4: all h1 reads done; smem base reusable for y

  // ---- y = h + b4 + x -> LDS fp32 [64][260] ----
  float* yb = (float*)smem;
  {
    int cb = w * 16 + 4 * lh;
    const float4 bv = *(const float4*)(b4 + cb);
    #pragma unroll
    for (int m = 0; m < 4; ++m) {
      int row = 16 * m + ll;
      int node = n0 + row;
      float4 xv = {0.f, 0.f, 0.f, 0.f};
      if (node < NN) xv = *(const float4*)(x + (size_t)node * ND + cb);
      f4v o;
      o[0] = acc4[m][0] + bv.x + xv.x;
      o[1] = acc4[m][1] + bv.y + xv.y;
      o[2] = acc4[m][2] + bv.z + xv.z;
      o[3] = acc4[m][3] + bv.w + xv.w;
      *(f4v*)(yb + row * 260 + cb) = o;
    }
  }
  __syncthreads();   // barrier 5

  // ---- LayerNorm: 16 threads per row ----
  {
    int row = tid >> 4, sub = tid & 15;
    int node = n0 + row;
    float v[16];
    float sum = 0.f, ssq = 0.f;
    #pragma unroll
    for (int i = 0; i < 4; ++i) {
      const float4 t = *(const float4*)(yb + row * 260 + (i * 16 + sub) * 4);
      v[i * 4 + 0] = t.x; v[i * 4 + 1] = t.y; v[i * 4 + 2] = t.z; v[i * 4 + 3] = t.w;
      sum += t.x + t.y + t.z + t.w;
      ssq += t.x * t.x + t.y * t.y + t.z * t.z + t.w * t.w;
    }
    #pragma unroll
    for (int d = 1; d < 16; d <<= 1) {
      sum += __shfl_xor(sum, d);
      ssq += __shfl_xor(ssq, d);
    }
    float mu = sum * (1.f / 256.f);
    float var = ssq * (1.f / 256.f) - mu * mu;
    float rstd = rsqrtf(var + 1e-5f);
    if (node < NN) {
      #pragma unroll
      for (int i = 0; i < 4; ++i) {
        int c = (i * 16 + sub) * 4;
        const float4 g = *(const float4*)(gamma + c);
        const float4 be = *(const float4*)(beta + c);
        float4 o;
        o.x = (v[i * 4 + 0] - mu) * rstd * g.x + be.x;
        o.y = (v[i * 4 + 1] - mu) * rstd * g.y + be.y;
        o.z = (v[i * 4 + 2] - mu) * rstd * g.z + be.z;
        o.w = (v[i * 4 + 3] - mu) * rstd * g.w + be.w;
        *(float4*)(out + (size_t)node * ND + c) = o;
      }
    }
  }
}

extern "C" void kernel_launch(void* const* d_in, const int* in_sizes, int n_in,
                              void* d_out, int out_size, void* d_ws, size_t ws_size,
                              hipStream_t stream) {
  const float* x    = (const float*)d_in[0];
  const float* ea   = (const float*)d_in[1];
  const float* u    = (const float*)d_in[2];
  const float* W1   = (const float*)d_in[3];
  const float* b1   = (const float*)d_in[4];
  const float* W2   = (const float*)d_in[5];
  const float* b2   = (const float*)d_in[6];
  const float* W3   = (const float*)d_in[7];
  const float* b3   = (const float*)d_in[8];
  const float* W4   = (const float*)d_in[9];
  const float* b4   = (const float*)d_in[10];
  const float* gamma = (const float*)d_in[11];
  const float* beta  = (const float*)d_in[12];
  const int* eidx   = (const int*)d_in[13];
  const int* batch  = (const int*)d_in[14];
  float* out = (float*)d_out;

  char* p = (char*)d_ws;
  size_t off = 0;
  auto take = [&](size_t n) { char* r = p + off; off = (off + n + 255) & ~(size_t)255; return r; };
  short* xbf = (short*)take((size_t)NN * ND * 2);
  short* w1p = (short*)take((size_t)384 * 512 * 2);
  short* w2p = (short*)take((size_t)512 * 128 * 2);
  short* w3p = (short*)take((size_t)448 * 1024 * 2);
  short* w4p = (short*)take((size_t)1024 * 256 * 2);
  unsigned int* cnt = (unsigned int*)take((size_t)NN * 4);
  int* elist = (int*)take((size_t)NN * MAXDEG * 4);
  unsigned short* aggbf = (unsigned short*)take((size_t)NN * ED * 2);
  unsigned short* ebuf = (unsigned short*)take((size_t)NE * ED * 2);

  const int* erow = eidx;
  const int* ecol = eidx + NE;

  hipMemsetAsync(cnt, 0, (size_t)NN * 4, stream);
  {
    const int total = J5 + J0 + J1 + J2 + J3 + J4;
    prep_kernel<<<(total + 255) / 256, 256, 0, stream>>>(x, xbf, W1, W2, W3, W4,
                                                         w1p, w2p, w3p, w4p,
                                                         ecol, cnt, elist);
  }
  edge_kernel<<<(NE + 127) / 128, 1024, 0, stream>>>(xbf, ea, w1p, b1, w2p, b2, erow, ebuf);
  agg_kernel<<<(NN + 3) / 4, 256, 0, stream>>>(ebuf, elist, cnt, aggbf);
  node_kernel<<<(NN + 63) / 64, 1024, 0, stream>>>(x, xbf, u, w3p, b3, w4p, b4,
                                                   gamma, beta, batch, aggbf, out);
}